// Round 6
// baseline (1303.258 us; speedup 1.0000x reference)
//
#include <hip/hip_runtime.h>
#include <math.h>

// ---------------------------------------------------------------------------
// Model_Recursive_LSTM_v2 — round 6: everything on split-bf16 MFMA.
//
// R5 counters: L0 = 316us, MfmaUtil 8.4%, VALUBusy 30% (in-loop f32->bf16
// split), FETCH 313MB (A streamed 10x, row-major block order). Fixes:
//   1. Pre-split A0 once (ws_size-guarded; fallback = in-register split).
//   2. grid.x = column tiles -> A row-panel L2-reused, W L2-resident.
//   3. 128x128 block tile (2x2 waves of 64x64) -> L2 traffic 49 FLOP/B,
//      under the per-CU L2 bandwidth budget; no LDS, no barriers.
//   4. All tail GEMMs (LSTM step, XW, concat, regression) now MFMA too;
//      lstm_gate writes h as bf16 hi/lo pair; t=0 h.Whh GEMM skipped (h0=0).
// Numerics: x = hi + lo (RN bf16), 3 MFMAs (hh+hl+lh), f32 accum ->
// ~2^-18 relative; verified absmax 0.0 in R5.
// ---------------------------------------------------------------------------

typedef __attribute__((ext_vector_type(8))) short bf16x8;
typedef __attribute__((ext_vector_type(4))) float f32x4;
typedef __attribute__((ext_vector_type(4))) unsigned short us4;
typedef unsigned short ushort_t;
typedef unsigned int uint_t;

__device__ __forceinline__ float elu1(float x) { return x > 0.f ? x : expm1f(x); }
__device__ __forceinline__ float sigm(float x) { return 1.f / (1.f + expf(-x)); }

__device__ __forceinline__ ushort_t f2bf(float f) {
    union { float f; uint_t u; } v; v.f = f;
    uint_t u = v.u;
    uint_t r = u + 0x7FFFu + ((u >> 16) & 1u);   // round-to-nearest-even
    return (ushort_t)(r >> 16);
}
__device__ __forceinline__ float bf2f(ushort_t h) {
    union { uint_t u; float f; } v; v.u = ((uint_t)h) << 16;
    return v.f;
}
__device__ __forceinline__ void split2(float x, ushort_t& hi, ushort_t& lo) {
    ushort_t h = f2bf(x);
    hi = h;
    lo = f2bf(x - bf2f(h));
}

__device__ __forceinline__ bf16x8 ld8(const ushort_t* p) { return *(const bf16x8*)p; }

__device__ __forceinline__ void load_split_f32(const float* p, bf16x8& h8, bf16x8& l8) {
    const float4* q = (const float4*)p;
    float4 a = q[0], b = q[1];
    float v[8] = {a.x, a.y, a.z, a.w, b.x, b.y, b.z, b.w};
#pragma unroll
    for (int i = 0; i < 8; ++i) {
        ushort_t h, l; split2(v[i], h, l);
        h8[i] = (short)h; l8[i] = (short)l;
    }
}

// C = act(A * W^T + bias). 128x128 block tile, 4 waves (2x2), each wave a
// 64x64 tile of 4x4 16x16x32 fragments. A: M x lda (f32 if AF32 else bf16
// hi/lo planes). W: bf16 hi/lo planes, Np x ldw with Np a multiple of 128
// (zero-padded rows/cols). Grid: x = Np/128 (fast -> A panel L2-reuse),
// y = M/128 (M must be a multiple of 128).
// OUTPAIR: write bf16 hi/lo planes M x ldc (cols in [N,ldc) zeroed); else
// f32 M x N.
template <bool AF32, bool OUTPAIR>
__global__ __launch_bounds__(256)
void gemm_mfma(const void* __restrict__ Ap, const void* __restrict__ Alop, int lda,
               const ushort_t* __restrict__ Whi, const ushort_t* __restrict__ Wlo, int ldw,
               const float* __restrict__ bias,
               float* __restrict__ Cf, ushort_t* __restrict__ Chi, ushort_t* __restrict__ Clo,
               int ldc, int M, int N, int Kp, int act)
{
    const int lane = threadIdx.x & 63;
    const int wave = threadIdx.x >> 6;
    const int wm = wave & 1, wn = wave >> 1;          // 2x2 waves -> 128x128
    const int r16 = lane & 15;
    const int kb  = (lane >> 4) << 3;                 // k base: 0,8,16,24
    const int bm = blockIdx.y * 128 + wm * 64;
    const int bn = blockIdx.x * 128 + wn * 64;

    f32x4 acc[4][4] = {};

    size_t aoff[4];
    const ushort_t* wh[4];
    const ushort_t* wl[4];
#pragma unroll
    for (int i = 0; i < 4; ++i) {
        aoff[i] = (size_t)(bm + i * 16 + r16) * lda + kb;
        wh[i] = Whi + (size_t)(bn + i * 16 + r16) * ldw + kb;
        wl[i] = Wlo + (size_t)(bn + i * 16 + r16) * ldw + kb;
    }

    for (int k = 0; k < Kp; k += 32) {
        bf16x8 ah[4], al[4], bh[4], bl[4];
#pragma unroll
        for (int i = 0; i < 4; ++i) {
            if constexpr (AF32) {
                load_split_f32((const float*)Ap + aoff[i] + k, ah[i], al[i]);
            } else {
                ah[i] = ld8((const ushort_t*)Ap + aoff[i] + k);
                al[i] = ld8((const ushort_t*)Alop + aoff[i] + k);
            }
            bh[i] = ld8(wh[i] + k);
            bl[i] = ld8(wl[i] + k);
        }
#pragma unroll
        for (int ms = 0; ms < 4; ++ms)
#pragma unroll
        for (int ns = 0; ns < 4; ++ns) {
            acc[ms][ns] = __builtin_amdgcn_mfma_f32_16x16x32_bf16(ah[ms], bh[ns], acc[ms][ns], 0, 0, 0);
            acc[ms][ns] = __builtin_amdgcn_mfma_f32_16x16x32_bf16(ah[ms], bl[ns], acc[ms][ns], 0, 0, 0);
            acc[ms][ns] = __builtin_amdgcn_mfma_f32_16x16x32_bf16(al[ms], bh[ns], acc[ms][ns], 0, 0, 0);
        }
    }

    const int rbase = (lane >> 4) << 2;               // D row base: 0,4,8,12
#pragma unroll
    for (int ms = 0; ms < 4; ++ms)
#pragma unroll
    for (int ns = 0; ns < 4; ++ns) {
        const int gc = bn + ns * 16 + r16;
#pragma unroll
        for (int r = 0; r < 4; ++r) {
            const int gr = bm + ms * 16 + rbase + r;
            float v = acc[ms][ns][r];
            if constexpr (OUTPAIR) {
                if (gc < ldc) {
                    float o = 0.f;
                    if (gc < N) {
                        o = v + (bias ? bias[gc] : 0.f);
                        if (act) o = elu1(o);
                    }
                    ushort_t hh, ll; split2(o, hh, ll);
                    Chi[(size_t)gr * ldc + gc] = hh;
                    Clo[(size_t)gr * ldc + gc] = ll;
                }
            } else {
                if (gc < N) {
                    float o = v + (bias ? bias[gc] : 0.f);
                    if (act) o = elu1(o);
                    Cf[(size_t)gr * N + gc] = o;
                }
            }
        }
    }
}

// f32 weight slice [R x C] at (0, soff) of a R x sld matrix -> bf16 hi/lo
// planes [Rp x Cp], zero-padded.
__global__ void conv_w(const float* __restrict__ src, int sld, int soff,
                       int R, int C, ushort_t* __restrict__ dhi,
                       ushort_t* __restrict__ dlo, int Rp, int Cp)
{
    int idx = blockIdx.x * blockDim.x + threadIdx.x;
    if (idx >= Rp * Cp) return;
    int r = idx / Cp, c = idx - r * Cp;
    float v = (r < R && c < C) ? src[r * sld + soff + c] : 0.f;
    ushort_t h, l; split2(v, h, l);
    dhi[idx] = h; dlo[idx] = l;
}

// Pre-split ast (16384x1024 f32) into bf16 hi/lo planes, float4-vectorized.
__global__ void conv_a0(const float* __restrict__ src, ushort_t* __restrict__ dhi,
                        ushort_t* __restrict__ dlo)
{
    int idx = blockIdx.x * blockDim.x + threadIdx.x;
    if (idx >= 16384 * 256) return;
    float4 v = ((const float4*)src)[idx];
    float x[4] = {v.x, v.y, v.z, v.w};
    us4 h, l;
#pragma unroll
    for (int i = 0; i < 4; ++i) {
        ushort_t hh, ll; split2(x[i], hh, ll);
        h[i] = hh; l[i] = ll;
    }
    ((us4*)dhi)[idx] = h;
    ((us4*)dlo)[idx] = l;
}

// Gate update. G (rows x 720 f32, nullptr for t=0 where h=0), XW rows
// interleaved by T. Writes c (rows x 180 f32) and h as bf16 hi/lo pair
// (rows x 192; pad cols pre-zeroed by memset).
__global__ void lstm_gate(ushort_t* __restrict__ h_hi, ushort_t* __restrict__ h_lo,
                          float* __restrict__ c,
                          const float* __restrict__ G, const float* __restrict__ XW,
                          int rows, int T, int t)
{
    int idx = blockIdx.x * blockDim.x + threadIdx.x;
    if (idx >= rows * 180) return;
    int n = idx / 180, e = idx - n * 180;
    const float* xw = XW + ((size_t)n * T + t) * 720;
    float gi = xw[e], gf = xw[e + 180], gg = xw[e + 360], go = xw[e + 540];
    if (G) {
        const float* g = G + (size_t)n * 720;
        gi += g[e]; gf += g[e + 180]; gg += g[e + 360]; go += g[e + 540];
    }
    float cv = sigm(gf) * c[idx] + sigm(gi) * tanhf(gg);
    c[idx] = cv;
    float hv = sigm(go) * tanhf(cv);
    ushort_t hh, ll; split2(hv, hh, ll);
    h_hi[(size_t)n * 192 + e] = hh;
    h_lo[(size_t)n * 192 + e] = ll;
}

// leaf inputs (bf16 pair): row r = (j*256+b)*8 + t  <-  embed row b*64+8j+t
__global__ void gather_leaf_bf(const ushort_t* __restrict__ ehi, const ushort_t* __restrict__ elo,
                               ushort_t* __restrict__ xhi, ushort_t* __restrict__ xlo)
{
    int idx = blockIdx.x * blockDim.x + threadIdx.x;
    if (idx >= 12288 * 192) return;
    int r = idx / 192, e = idx - r * 192;
    int t = r & 7, nb = r >> 3;
    int b = nb & 255, j = nb >> 8;
    int s = (b * 64 + 8 * j + t) * 192 + e;
    xhi[idx] = ehi[s];
    xlo[idx] = elo[s];
}

// mid inputs: row r = (i*256+b)*2 + t  <-  leaf_state row (2i+t)*256 + b
__global__ void gather_mid_bf(const ushort_t* __restrict__ shi, const ushort_t* __restrict__ slo,
                              ushort_t* __restrict__ dhi, ushort_t* __restrict__ dlo)
{
    int idx = blockIdx.x * blockDim.x + threadIdx.x;
    if (idx >= 1536 * 192) return;
    int r = idx / 192, e = idx - r * 192;
    int t = r & 1, m = r >> 1;
    int b = m & 255, i = m >> 8;
    int s = ((2 * i + t) * 256 + b) * 192 + e;
    dhi[idx] = shi[s];
    dlo[idx] = slo[s];
}

// root inputs: row r = b*3 + t  <-  mid_state row t*256 + b
__global__ void gather_root_bf(const ushort_t* __restrict__ shi, const ushort_t* __restrict__ slo,
                               ushort_t* __restrict__ dhi, ushort_t* __restrict__ dlo)
{
    int idx = blockIdx.x * blockDim.x + threadIdx.x;
    if (idx >= 768 * 192) return;
    int r = idx / 192, e = idx - r * 192;
    int b = r / 3, t = r - b * 3;
    int s = (t * 256 + b) * 192 + e;
    dhi[idx] = shi[s];
    dlo[idx] = slo[s];
}

__global__ void bias_prep(const float* __restrict__ cl_bih, const float* __restrict__ cl_bhh,
                          const float* __restrict__ nl_bih, const float* __restrict__ nl_bhh,
                          const float* __restrict__ cc_w0, const float* __restrict__ cc_b0,
                          const float* __restrict__ no_nodes, const float* __restrict__ no_comps,
                          float* __restrict__ clb, float* __restrict__ nlb,
                          float* __restrict__ b1, float* __restrict__ b2)
{
    int tid = blockIdx.x * blockDim.x + threadIdx.x;
    if (tid < 720) {
        clb[tid] = cl_bih[tid] + cl_bhh[tid];
    } else if (tid < 1440) {
        int o = tid - 720;
        nlb[o] = nl_bih[o] + nl_bhh[o];
    } else if (tid < 1640) {
        int o = tid - 1440;
        float s = cc_b0[o];
        for (int e = 0; e < 180; ++e) s = fmaf(no_nodes[e], cc_w0[o * 360 + e], s);
        b1[o] = s;   // leaf: nodes half is constant no_nodes (cols 0:180)
    } else if (tid < 1840) {
        int o = tid - 1640;
        float s = cc_b0[o];
        for (int e = 0; e < 180; ++e) s = fmaf(no_comps[e], cc_w0[o * 360 + 180 + e], s);
        b2[o] = s;   // interior: comps half is constant no_comps (cols 180:360)
    }
}

__global__ void pred_kernel(const float* __restrict__ x, const float* __restrict__ pw,
                            const float* __restrict__ pb, float* __restrict__ out)
{
    int b = blockIdx.x * blockDim.x + threadIdx.x;
    if (b >= 256) return;
    float s = pb[0];
#pragma unroll 4
    for (int e = 0; e < 180; ++e) s = fmaf(x[b * 180 + e], pw[e], s);
    out[b] = s;
}

extern "C" void kernel_launch(void* const* d_in, const int* in_sizes, int n_in,
                              void* d_out, int out_size, void* d_ws, size_t ws_size,
                              hipStream_t stream)
{
    const float* ast    = (const float*)d_in[0];   // 256x64x1024
    const float* ce_w0  = (const float*)d_in[1];   // 600x1024
    const float* ce_b0  = (const float*)d_in[2];
    const float* ce_w1  = (const float*)d_in[3];   // 350x600
    const float* ce_b1  = (const float*)d_in[4];
    const float* ce_w2  = (const float*)d_in[5];   // 200x350
    const float* ce_b2  = (const float*)d_in[6];
    const float* ce_w3  = (const float*)d_in[7];   // 180x200
    const float* ce_b3  = (const float*)d_in[8];
    const float* cc_w0  = (const float*)d_in[9];   // 200x360
    const float* cc_b0  = (const float*)d_in[10];
    const float* cc_w1  = (const float*)d_in[11];  // 180x200
    const float* cc_b1  = (const float*)d_in[12];
    const float* rg_w0  = (const float*)d_in[13];  // 200x180
    const float* rg_b0  = (const float*)d_in[14];
    const float* rg_w1  = (const float*)d_in[15];  // 180x200
    const float* rg_b1  = (const float*)d_in[16];
    const float* pred_w = (const float*)d_in[17];  // 1x180
    const float* pred_b = (const float*)d_in[18];
    const float* cl_Wih = (const float*)d_in[19];  // 720x180
    const float* cl_Whh = (const float*)d_in[20];
    const float* cl_bih = (const float*)d_in[21];
    const float* cl_bhh = (const float*)d_in[22];
    const float* nl_Wih = (const float*)d_in[23];
    const float* nl_Whh = (const float*)d_in[24];
    const float* nl_bih = (const float*)d_in[25];
    const float* nl_bhh = (const float*)d_in[26];
    const float* no_comps = (const float*)d_in[27]; // 1x180
    const float* no_nodes = (const float*)d_in[28]; // 1x180
    float* out = (float*)d_out;                     // 256 f32

    char* ws = (char*)d_ws;

    // ---- workspace layout ----
    // PRE path (needs 114,523,136 B): Z0 = 67.1 MB (A0 pair -> A2 -> EM -> XWl)
    // FALLBACK (83,065,856 B):        Z0 = 35.65 MB (A2 -> EM -> XWl)
    const size_t Z1SZ = 39845888;   // A1 pair region
    const size_t WTSZ = 7560192;
    const bool pre = ws_size >= (size_t)67108864 + Z1SZ + WTSZ + 8192;
    const size_t z0sz = pre ? 67108864 : 35651584;

    char* Z0 = ws;
    char* Z1 = ws + z0sz;
    char* WT = Z1 + Z1SZ;
    char* BI = WT + WTSZ;

    // Z0 tenants (sequential lifetimes)
    ushort_t* A0hi = (ushort_t*)Z0;                       // 16384x1024 (PRE only)
    ushort_t* A0lo = (ushort_t*)(Z0 + 33554432);
    ushort_t* A2hi = (ushort_t*)Z0;                       // 16384x352
    ushort_t* A2lo = (ushort_t*)(Z0 + 11534336);
    ushort_t* EMhi = (ushort_t*)Z0;                       // embed 16384x192
    ushort_t* EMlo = (ushort_t*)(Z0 + 6291456);
    float*    XWl  = (float*)Z0;                          // 12288x720 f32

    // Z1 tenants
    ushort_t* A1hi = (ushort_t*)Z1;                       // 16384x608
    ushort_t* A1lo = (ushort_t*)(Z1 + 19922944);
    ushort_t* A3hi = (ushort_t*)Z1;                       // 16384x224
    ushort_t* A3lo = (ushort_t*)(Z1 + 7340032);
    ushort_t* XGhi = (ushort_t*)Z1;                       // Xg 12288x192
    ushort_t* XGlo = (ushort_t*)(Z1 + 4718592);
    char* S = Z1 + 9437184;                               // smalls (~20.4 MB)

    ushort_t* hl_hi = (ushort_t*)(S);                     // 1536x192
    ushort_t* hl_lo = (ushort_t*)(S + 589824);
    float*    c_l   = (float*)(S + 1179648);              // 1536x180
    float*    G     = (float*)(S + 2285568);              // up to 1536x720
    ushort_t* ls_hi = (ushort_t*)(S + 6709248);           // leaf_state 1536x192
    ushort_t* ls_lo = (ushort_t*)(S + 7299072);
    ushort_t* y2_hi = (ushort_t*)(S + 7888896);           // y200 1536x224
    ushort_t* y2_lo = (ushort_t*)(S + 8577024);
    ushort_t* x2_hi = (ushort_t*)(S + 9265152);           // Xg2 1536x192
    ushort_t* x2_lo = (ushort_t*)(S + 9854976);
    float*    XW2   = (float*)(S + 10444800);             // 1536x720
    ushort_t* hm_hi = (ushort_t*)(S + 14868480);          // 768x192
    ushort_t* hm_lo = (ushort_t*)(S + 15163392);
    float*    c_m   = (float*)(S + 15458304);             // 768x180
    ushort_t* ms_hi = (ushort_t*)(S + 16011264);          // mid_state 768x192
    ushort_t* ms_lo = (ushort_t*)(S + 16306176);
    ushort_t* x3_hi = (ushort_t*)(S + 16601088);          // Xg3 768x192
    ushort_t* x3_lo = (ushort_t*)(S + 16896000);
    float*    XW3   = (float*)(S + 17190912);             // 768x720
    ushort_t* hr_hi = (ushort_t*)(S + 19402752);          // 256x192
    ushort_t* hr_lo = (ushort_t*)(S + 19501056);
    float*    c_r   = (float*)(S + 19599360);             // 256x180
    ushort_t* pg_hi = (ushort_t*)(S + 19783680);          // prog 256x192
    ushort_t* pg_lo = (ushort_t*)(S + 19881984);
    ushort_t* r2_hi = (ushort_t*)(S + 19980288);          // r200 256x224
    ushort_t* r2_lo = (ushort_t*)(S + 20094976);
    float*    r180  = (float*)(S + 20209664);             // 256x180

    // WT tenants (all Rp multiples of 128, Cp multiples of 32)
    ushort_t* w0hi  = (ushort_t*)(WT);                    // 640x1024
    ushort_t* w0lo  = (ushort_t*)(WT + 1310720);
    ushort_t* w1hi  = (ushort_t*)(WT + 2621440);          // 384x608
    ushort_t* w1lo  = (ushort_t*)(WT + 3088384);
    ushort_t* w2hi  = (ushort_t*)(WT + 3555328);          // 256x352
    ushort_t* w2lo  = (ushort_t*)(WT + 3735552);
    ushort_t* w3hi  = (ushort_t*)(WT + 3915776);          // 256x224
    ushort_t* w3lo  = (ushort_t*)(WT + 4030464);
    ushort_t* wiC_h = (ushort_t*)(WT + 4145152);          // cl_Wih 768x192
    ushort_t* wiC_l = (ushort_t*)(WT + 4440064);
    ushort_t* whC_h = (ushort_t*)(WT + 4734976);          // cl_Whh 768x192
    ushort_t* whC_l = (ushort_t*)(WT + 5029888);
    ushort_t* wiN_h = (ushort_t*)(WT + 5324800);          // nl_Wih 768x192
    ushort_t* wiN_l = (ushort_t*)(WT + 5619712);
    ushort_t* whN_h = (ushort_t*)(WT + 5914624);          // nl_Whh 768x192
    ushort_t* whN_l = (ushort_t*)(WT + 6209536);
    ushort_t* c0L_h = (ushort_t*)(WT + 6504448);          // cc_w0 cols 180:360, 256x192
    ushort_t* c0L_l = (ushort_t*)(WT + 6602752);
    ushort_t* c0I_h = (ushort_t*)(WT + 6701056);          // cc_w0 cols 0:180, 256x192
    ushort_t* c0I_l = (ushort_t*)(WT + 6799360);
    ushort_t* c1_h  = (ushort_t*)(WT + 6897664);          // cc_w1 256x224
    ushort_t* c1_l  = (ushort_t*)(WT + 7012352);
    ushort_t* rg0_h = (ushort_t*)(WT + 7127040);          // rg_w0 256x192
    ushort_t* rg0_l = (ushort_t*)(WT + 7225344);
    ushort_t* rg1_h = (ushort_t*)(WT + 7323648);          // rg_w1 256x224
    ushort_t* rg1_l = (ushort_t*)(WT + 7438336);

    float* clb = (float*)BI;
    float* nlb = (float*)(BI + 2880);
    float* b1  = (float*)(BI + 5760);
    float* b2  = (float*)(BI + 6560);

    // ---- 0. conversions + folded biases ----
    if (pre)
        conv_a0<<<16384, 256, 0, stream>>>(ast, A0hi, A0lo);
    conv_w<<<(640*1024 + 255)/256, 256, 0, stream>>>(ce_w0, 1024, 0, 600, 1024, w0hi, w0lo, 640, 1024);
    conv_w<<<(384*608 + 255)/256, 256, 0, stream>>>(ce_w1, 600, 0, 350, 600, w1hi, w1lo, 384, 608);
    conv_w<<<(256*352 + 255)/256, 256, 0, stream>>>(ce_w2, 350, 0, 200, 350, w2hi, w2lo, 256, 352);
    conv_w<<<(256*224 + 255)/256, 256, 0, stream>>>(ce_w3, 200, 0, 180, 200, w3hi, w3lo, 256, 224);
    conv_w<<<(768*192 + 255)/256, 256, 0, stream>>>(cl_Wih, 180, 0, 720, 180, wiC_h, wiC_l, 768, 192);
    conv_w<<<(768*192 + 255)/256, 256, 0, stream>>>(cl_Whh, 180, 0, 720, 180, whC_h, whC_l, 768, 192);
    conv_w<<<(768*192 + 255)/256, 256, 0, stream>>>(nl_Wih, 180, 0, 720, 180, wiN_h, wiN_l, 768, 192);
    conv_w<<<(768*192 + 255)/256, 256, 0, stream>>>(nl_Whh, 180, 0, 720, 180, whN_h, whN_l, 768, 192);
    conv_w<<<(256*192 + 255)/256, 256, 0, stream>>>(cc_w0, 360, 180, 200, 180, c0L_h, c0L_l, 256, 192);
    conv_w<<<(256*192 + 255)/256, 256, 0, stream>>>(cc_w0, 360, 0, 200, 180, c0I_h, c0I_l, 256, 192);
    conv_w<<<(256*224 + 255)/256, 256, 0, stream>>>(cc_w1, 200, 0, 180, 200, c1_h, c1_l, 256, 224);
    conv_w<<<(256*192 + 255)/256, 256, 0, stream>>>(rg_w0, 180, 0, 200, 180, rg0_h, rg0_l, 256, 192);
    conv_w<<<(256*224 + 255)/256, 256, 0, stream>>>(rg_w1, 200, 0, 180, 200, rg1_h, rg1_l, 256, 224);
    bias_prep<<<(1840 + 255)/256, 256, 0, stream>>>(
        cl_bih, cl_bhh, nl_bih, nl_bhh, cc_w0, cc_b0, no_nodes, no_comps,
        clb, nlb, b1, b2);

    dim3 blk(256);

    // ---- 1. comp-embedding MLP (ELU fused, bf16-pair epilogue) ----
    if (pre)
        gemm_mfma<false, true><<<dim3(5, 128), blk, 0, stream>>>(
            A0hi, A0lo, 1024, w0hi, w0lo, 1024, ce_b0,
            nullptr, A1hi, A1lo, 608, 16384, 600, 1024, 1);
    else
        gemm_mfma<true, true><<<dim3(5, 128), blk, 0, stream>>>(
            ast, nullptr, 1024, w0hi, w0lo, 1024, ce_b0,
            nullptr, A1hi, A1lo, 608, 16384, 600, 1024, 1);
    gemm_mfma<false, true><<<dim3(3, 128), blk, 0, stream>>>(
        A1hi, A1lo, 608, w1hi, w1lo, 608, ce_b1,
        nullptr, A2hi, A2lo, 352, 16384, 350, 608, 1);
    gemm_mfma<false, true><<<dim3(2, 128), blk, 0, stream>>>(
        A2hi, A2lo, 352, w2hi, w2lo, 352, ce_b2,
        nullptr, A3hi, A3lo, 224, 16384, 200, 352, 1);
    gemm_mfma<false, true><<<dim3(2, 128), blk, 0, stream>>>(
        A3hi, A3lo, 224, w3hi, w3lo, 224, ce_b3,
        nullptr, EMhi, EMlo, 192, 16384, 180, 224, 1);

    // ---- 2. leaf LSTM: batch 1536 (6 leaves x 256), T=8 ----
    gather_leaf_bf<<<(12288*192 + 255)/256, 256, 0, stream>>>(EMhi, EMlo, XGhi, XGlo);
    gemm_mfma<false, false><<<dim3(6, 96), blk, 0, stream>>>(
        XGhi, XGlo, 192, wiC_h, wiC_l, 192, clb,
        XWl, nullptr, nullptr, 0, 12288, 720, 192, 0);
    hipMemsetAsync(S, 0, 2285568, stream);  // hl pair + c_l
    for (int t = 0; t < 8; ++t) {
        if (t > 0)
            gemm_mfma<false, false><<<dim3(6, 12), blk, 0, stream>>>(
                hl_hi, hl_lo, 192, whC_h, whC_l, 192, nullptr,
                G, nullptr, nullptr, 0, 1536, 720, 192, 0);
        lstm_gate<<<(1536*180 + 255)/256, 256, 0, stream>>>(
            hl_hi, hl_lo, c_l, t ? G : nullptr, XWl, 1536, 8, t);
    }
    // leaf concat: comps half of cc_w0, no_nodes folded in b1
    gemm_mfma<false, true><<<dim3(2, 12), blk, 0, stream>>>(
        hl_hi, hl_lo, 192, c0L_h, c0L_l, 192, b1,
        nullptr, y2_hi, y2_lo, 224, 1536, 200, 192, 1);
    gemm_mfma<false, true><<<dim3(2, 12), blk, 0, stream>>>(
        y2_hi, y2_lo, 224, c1_h, c1_l, 224, cc_b1,
        nullptr, ls_hi, ls_lo, 192, 1536, 180, 224, 1);

    // ---- 3. mid LSTM: batch 768 (3 mids x 256), T=2 ----
    gather_mid_bf<<<(1536*192 + 255)/256, 256, 0, stream>>>(ls_hi, ls_lo, x2_hi, x2_lo);
    gemm_mfma<false, false><<<dim3(6, 12), blk, 0, stream>>>(
        x2_hi, x2_lo, 192, wiN_h, wiN_l, 192, nlb,
        XW2, nullptr, nullptr, 0, 1536, 720, 192, 0);
    hipMemsetAsync(S + 14868480, 0, 1142784, stream);  // hm pair + c_m
    for (int t = 0; t < 2; ++t) {
        if (t > 0)
            gemm_mfma<false, false><<<dim3(6, 6), blk, 0, stream>>>(
                hm_hi, hm_lo, 192, whN_h, whN_l, 192, nullptr,
                G, nullptr, nullptr, 0, 768, 720, 192, 0);
        lstm_gate<<<(768*180 + 255)/256, 256, 0, stream>>>(
            hm_hi, hm_lo, c_m, t ? G : nullptr, XW2, 768, 2, t);
    }
    // interior concat: nodes half of cc_w0, no_comps folded in b2
    gemm_mfma<false, true><<<dim3(2, 6), blk, 0, stream>>>(
        hm_hi, hm_lo, 192, c0I_h, c0I_l, 192, b2,
        nullptr, y2_hi, y2_lo, 224, 768, 200, 192, 1);
    gemm_mfma<false, true><<<dim3(2, 6), blk, 0, stream>>>(
        y2_hi, y2_lo, 224, c1_h, c1_l, 224, cc_b1,
        nullptr, ms_hi, ms_lo, 192, 768, 180, 224, 1);

    // ---- 4. root LSTM: batch 256, T=3 ----
    gather_root_bf<<<(768*192 + 255)/256, 256, 0, stream>>>(ms_hi, ms_lo, x3_hi, x3_lo);
    gemm_mfma<false, false><<<dim3(6, 6), blk, 0, stream>>>(
        x3_hi, x3_lo, 192, wiN_h, wiN_l, 192, nlb,
        XW3, nullptr, nullptr, 0, 768, 720, 192, 0);
    hipMemsetAsync(S + 19402752, 0, 380928, stream);  // hr pair + c_r
    for (int t = 0; t < 3; ++t) {
        if (t > 0)
            gemm_mfma<false, false><<<dim3(6, 2), blk, 0, stream>>>(
                hr_hi, hr_lo, 192, whN_h, whN_l, 192, nullptr,
                G, nullptr, nullptr, 0, 256, 720, 192, 0);
        lstm_gate<<<(256*180 + 255)/256, 256, 0, stream>>>(
            hr_hi, hr_lo, c_r, t ? G : nullptr, XW3, 256, 3, t);
    }
    gemm_mfma<false, true><<<dim3(2, 2), blk, 0, stream>>>(
        hr_hi, hr_lo, 192, c0I_h, c0I_l, 192, b2,
        nullptr, y2_hi, y2_lo, 224, 256, 200, 192, 1);
    gemm_mfma<false, true><<<dim3(2, 2), blk, 0, stream>>>(
        y2_hi, y2_lo, 224, c1_h, c1_l, 224, cc_b1,
        nullptr, pg_hi, pg_lo, 192, 256, 180, 224, 1);

    // ---- 5. regression + prediction ----
    gemm_mfma<false, true><<<dim3(2, 2), blk, 0, stream>>>(
        pg_hi, pg_lo, 192, rg0_h, rg0_l, 192, rg_b0,
        nullptr, r2_hi, r2_lo, 224, 256, 200, 192, 1);
    gemm_mfma<false, false><<<dim3(2, 2), blk, 0, stream>>>(
        r2_hi, r2_lo, 224, rg1_h, rg1_l, 224, rg_b1,
        r180, nullptr, nullptr, 0, 256, 180, 224, 1);
    pred_kernel<<<1, 256, 0, stream>>>(r180, pred_w, pred_b, out);
}

// Round 7
// 1065.874 us; speedup vs baseline: 1.2227x; 1.2227x over previous
//
#include <hip/hip_runtime.h>
#include <math.h>

// ---------------------------------------------------------------------------
// Model_Recursive_LSTM_v2 — round 7: LDS-staged split-bf16 MFMA GEMM (m97-style).
//
// R6 counters: L0 = 293us, MfmaUtil 8.8%, VALUBusy 9.5%, Occupancy 14.7% ->
// latency-bound direct-global operand feeding. Fix: global_load_lds staging
// (the compiler never auto-emits it) + 2-barrier K-loop, the HW-proven m97
// structure.
//
// gemm_lds: 128x128 tile, 4 waves (2x2 of 64x64), BK=32.
//   LDS = 4 planes {Ahi,Alo,Whi,Wlo} x 128rows x 32k bf16 = 32 KB, stored
//   FRAGMENT-CONTIGUOUS: strip t (16 rows) occupies 1024B at p*8192+t*1024,
//   lane l's MFMA chunk (row=l&15, k=(l>>4)*8..+8) at +l*16. global_load_lds
//   writes linearly (base+lane*16) so the per-lane GLOBAL address does the
//   permutation; ds_read_b128 at +lane*16 is conflict-free by construction.
//   Each wave stages exactly one plane (8 gload_lds/k-tile).
// Split numerics unchanged (hh+hl+lh, f32 accum; absmax 6.1e-5 in R6).
// All GEMMs (MLP, XW, LSTM-step, concat, regression) use gemm_lds; the
// in-register-split gemm_mfma is kept only for the small-ws fallback L0.
// ---------------------------------------------------------------------------

typedef __attribute__((ext_vector_type(8))) short bf16x8;
typedef __attribute__((ext_vector_type(4))) float f32x4;
typedef __attribute__((ext_vector_type(4))) unsigned short us4;
typedef unsigned short ushort_t;
typedef unsigned int uint_t;

__device__ __forceinline__ float elu1(float x) { return x > 0.f ? x : expm1f(x); }
__device__ __forceinline__ float sigm(float x) { return 1.f / (1.f + expf(-x)); }

__device__ __forceinline__ ushort_t f2bf(float f) {
    union { float f; uint_t u; } v; v.f = f;
    uint_t u = v.u;
    uint_t r = u + 0x7FFFu + ((u >> 16) & 1u);   // round-to-nearest-even
    return (ushort_t)(r >> 16);
}
__device__ __forceinline__ float bf2f(ushort_t h) {
    union { uint_t u; float f; } v; v.u = ((uint_t)h) << 16;
    return v.f;
}
__device__ __forceinline__ void split2(float x, ushort_t& hi, ushort_t& lo) {
    ushort_t h = f2bf(x);
    hi = h;
    lo = f2bf(x - bf2f(h));
}

__device__ __forceinline__ bf16x8 ld8(const ushort_t* p) { return *(const bf16x8*)p; }

__device__ __forceinline__ void load_split_f32(const float* p, bf16x8& h8, bf16x8& l8) {
    const float4* q = (const float4*)p;
    float4 a = q[0], b = q[1];
    float v[8] = {a.x, a.y, a.z, a.w, b.x, b.y, b.z, b.w};
#pragma unroll
    for (int i = 0; i < 8; ++i) {
        ushort_t h, l; split2(v[i], h, l);
        h8[i] = (short)h; l8[i] = (short)l;
    }
}

// async global -> LDS, 16 B per lane (lands at lds_base + lane*16)
__device__ __forceinline__ void gload16(const void* g, void* l) {
    __builtin_amdgcn_global_load_lds(
        (const __attribute__((address_space(1))) unsigned int*)g,
        (__attribute__((address_space(3))) unsigned int*)l,
        16, 0, 0);
}

// ---------------------------------------------------------------------------
// LDS-staged split-bf16 GEMM. C = act(A * W^T + bias).
// A: bf16 hi/lo planes, (grid.y*128) x lda.  W: bf16 hi/lo planes,
// (grid.x*128) x ldw (zero-padded). Kp % 32 == 0.
// OUTPAIR: bf16 hi/lo planes M x ldc (cols in [N,ldc) zeroed); else f32 M x N.
// ---------------------------------------------------------------------------
template <bool OUTPAIR>
__global__ __launch_bounds__(256)
void gemm_lds(const ushort_t* __restrict__ Ahi, const ushort_t* __restrict__ Alo, int lda,
              const ushort_t* __restrict__ Whi, const ushort_t* __restrict__ Wlo, int ldw,
              const float* __restrict__ bias,
              float* __restrict__ Cf, ushort_t* __restrict__ Chi, ushort_t* __restrict__ Clo,
              int ldc, int N, int Kp, int act)
{
    __shared__ ushort_t lds[4 * 4096];   // 4 planes x (8 strips x 1024 B)
    const int tid  = threadIdx.x;
    const int lane = tid & 63;
    const int wave = tid >> 6;
    const int wm = wave & 1;             // row half of 128x128 tile
    const int wn = wave >> 1;            // col half
    const int j16 = lane & 15;
    const int kq  = lane >> 4;           // k-slot 0..3 (8 bf16 each)
    const int bm = blockIdx.y * 128;
    const int bn = blockIdx.x * 128;

    // staging role: wave p stages plane p (0=Ahi,1=Alo,2=Whi,3=Wlo)
    const ushort_t* sbase = (wave == 0) ? Ahi : (wave == 1) ? Alo
                          : (wave == 2) ? Whi : Wlo;
    const int srow0 = (wave < 2) ? bm : bn;
    const int sld   = (wave < 2) ? lda : ldw;
    // per-lane fixed part: (row0 + j16)*ld + kq*8
    const size_t soff = (size_t)(srow0 + j16) * sld + kq * 8;
    char* const lplane = (char*)lds + wave * 8192;

    f32x4 acc[4][4] = {};

    for (int k0 = 0; k0 < Kp; k0 += 32) {
#pragma unroll
        for (int u = 0; u < 8; ++u) {    // 8 strips of 16 rows
            gload16(sbase + soff + (size_t)u * 16 * sld + k0, lplane + u * 1024);
        }
        __syncthreads();                 // drains vmcnt -> staged data visible

        bf16x8 ah[4], al[4], bh[4], bl[4];
#pragma unroll
        for (int i = 0; i < 4; ++i) {
            const int ta = (wm * 4 + i) * 1024 + lane * 16;
            const int tb = (wn * 4 + i) * 1024 + lane * 16;
            ah[i] = *(const bf16x8*)((const char*)lds +         ta);
            al[i] = *(const bf16x8*)((const char*)lds +  8192 + ta);
            bh[i] = *(const bf16x8*)((const char*)lds + 16384 + tb);
            bl[i] = *(const bf16x8*)((const char*)lds + 24576 + tb);
        }
#pragma unroll
        for (int ms = 0; ms < 4; ++ms)
#pragma unroll
        for (int ns = 0; ns < 4; ++ns) {
            acc[ms][ns] = __builtin_amdgcn_mfma_f32_16x16x32_bf16(ah[ms], bh[ns], acc[ms][ns], 0, 0, 0);
            acc[ms][ns] = __builtin_amdgcn_mfma_f32_16x16x32_bf16(ah[ms], bl[ns], acc[ms][ns], 0, 0, 0);
            acc[ms][ns] = __builtin_amdgcn_mfma_f32_16x16x32_bf16(al[ms], bh[ns], acc[ms][ns], 0, 0, 0);
        }
        __syncthreads();                 // protect LDS before next overwrite
    }

    const int rbase = kq << 2;           // D row base: 0,4,8,12
#pragma unroll
    for (int ms = 0; ms < 4; ++ms)
#pragma unroll
    for (int ns = 0; ns < 4; ++ns) {
        const int gc = bn + wn * 64 + ns * 16 + j16;
#pragma unroll
        for (int r = 0; r < 4; ++r) {
            const int gr = bm + wm * 64 + ms * 16 + rbase + r;
            float v = acc[ms][ns][r];
            if constexpr (OUTPAIR) {
                if (gc < ldc) {
                    float o = 0.f;
                    if (gc < N) {
                        o = v + (bias ? bias[gc] : 0.f);
                        if (act) o = elu1(o);
                    }
                    ushort_t hh, ll; split2(o, hh, ll);
                    Chi[(size_t)gr * ldc + gc] = hh;
                    Clo[(size_t)gr * ldc + gc] = ll;
                }
            } else {
                if (gc < N) {
                    float o = v + (bias ? bias[gc] : 0.f);
                    if (act) o = elu1(o);
                    Cf[(size_t)gr * N + gc] = o;
                }
            }
        }
    }
}

// ---------------------------------------------------------------------------
// Fallback L0 kernel (in-register split from f32 A) for small-ws deployments.
// ---------------------------------------------------------------------------
__global__ __launch_bounds__(256)
void gemm_mfma_f32a(const float* __restrict__ A, int lda,
                    const ushort_t* __restrict__ Whi, const ushort_t* __restrict__ Wlo, int ldw,
                    const float* __restrict__ bias,
                    ushort_t* __restrict__ Chi, ushort_t* __restrict__ Clo,
                    int ldc, int N, int Kp, int act)
{
    const int lane = threadIdx.x & 63;
    const int wave = threadIdx.x >> 6;
    const int wm = wave & 1, wn = wave >> 1;
    const int r16 = lane & 15;
    const int kb  = (lane >> 4) << 3;
    const int bm = blockIdx.y * 128 + wm * 64;
    const int bn = blockIdx.x * 128 + wn * 64;

    f32x4 acc[4][4] = {};
    size_t aoff[4];
    const ushort_t *wh[4], *wl[4];
#pragma unroll
    for (int i = 0; i < 4; ++i) {
        aoff[i] = (size_t)(bm + i * 16 + r16) * lda + kb;
        wh[i] = Whi + (size_t)(bn + i * 16 + r16) * ldw + kb;
        wl[i] = Wlo + (size_t)(bn + i * 16 + r16) * ldw + kb;
    }
    for (int k = 0; k < Kp; k += 32) {
        bf16x8 ah[4], al[4], bh[4], bl[4];
#pragma unroll
        for (int i = 0; i < 4; ++i) {
            load_split_f32(A + aoff[i] + k, ah[i], al[i]);
            bh[i] = ld8(wh[i] + k);
            bl[i] = ld8(wl[i] + k);
        }
#pragma unroll
        for (int ms = 0; ms < 4; ++ms)
#pragma unroll
        for (int ns = 0; ns < 4; ++ns) {
            acc[ms][ns] = __builtin_amdgcn_mfma_f32_16x16x32_bf16(ah[ms], bh[ns], acc[ms][ns], 0, 0, 0);
            acc[ms][ns] = __builtin_amdgcn_mfma_f32_16x16x32_bf16(ah[ms], bl[ns], acc[ms][ns], 0, 0, 0);
            acc[ms][ns] = __builtin_amdgcn_mfma_f32_16x16x32_bf16(al[ms], bh[ns], acc[ms][ns], 0, 0, 0);
        }
    }
    const int rbase = (lane >> 4) << 2;
#pragma unroll
    for (int ms = 0; ms < 4; ++ms)
#pragma unroll
    for (int ns = 0; ns < 4; ++ns) {
        const int gc = bn + ns * 16 + r16;
#pragma unroll
        for (int r = 0; r < 4; ++r) {
            const int gr = bm + ms * 16 + rbase + r;
            if (gc < ldc) {
                float o = 0.f;
                if (gc < N) {
                    o = acc[ms][ns][r] + bias[gc];
                    if (act) o = elu1(o);
                }
                ushort_t hh, ll; split2(o, hh, ll);
                Chi[(size_t)gr * ldc + gc] = hh;
                Clo[(size_t)gr * ldc + gc] = ll;
            }
        }
    }
}

// f32 weight slice [R x C] at (0, soff) of a R x sld matrix -> bf16 hi/lo
// planes [Rp x Cp], zero-padded.
__global__ void conv_w(const float* __restrict__ src, int sld, int soff,
                       int R, int C, ushort_t* __restrict__ dhi,
                       ushort_t* __restrict__ dlo, int Rp, int Cp)
{
    int idx = blockIdx.x * blockDim.x + threadIdx.x;
    if (idx >= Rp * Cp) return;
    int r = idx / Cp, c = idx - r * Cp;
    float v = (r < R && c < C) ? src[r * sld + soff + c] : 0.f;
    ushort_t h, l; split2(v, h, l);
    dhi[idx] = h; dlo[idx] = l;
}

// Pre-split ast (16384x1024 f32) into bf16 hi/lo planes, float4-vectorized.
__global__ void conv_a0(const float* __restrict__ src, ushort_t* __restrict__ dhi,
                        ushort_t* __restrict__ dlo)
{
    int idx = blockIdx.x * blockDim.x + threadIdx.x;
    if (idx >= 16384 * 256) return;
    float4 v = ((const float4*)src)[idx];
    float x[4] = {v.x, v.y, v.z, v.w};
    us4 h, l;
#pragma unroll
    for (int i = 0; i < 4; ++i) {
        ushort_t hh, ll; split2(x[i], hh, ll);
        h[i] = hh; l[i] = ll;
    }
    ((us4*)dhi)[idx] = h;
    ((us4*)dlo)[idx] = l;
}

// Gate update. G (rows x 720 f32, nullptr for t=0 where h=0), XW rows
// interleaved by T. Writes c (rows x 180 f32) and h as bf16 hi/lo pair
// (rows x 192; pad cols pre-zeroed by memset).
__global__ void lstm_gate(ushort_t* __restrict__ h_hi, ushort_t* __restrict__ h_lo,
                          float* __restrict__ c,
                          const float* __restrict__ G, const float* __restrict__ XW,
                          int rows, int T, int t)
{
    int idx = blockIdx.x * blockDim.x + threadIdx.x;
    if (idx >= rows * 180) return;
    int n = idx / 180, e = idx - n * 180;
    const float* xw = XW + ((size_t)n * T + t) * 720;
    float gi = xw[e], gf = xw[e + 180], gg = xw[e + 360], go = xw[e + 540];
    if (G) {
        const float* g = G + (size_t)n * 720;
        gi += g[e]; gf += g[e + 180]; gg += g[e + 360]; go += g[e + 540];
    }
    float cv = sigm(gf) * c[idx] + sigm(gi) * tanhf(gg);
    c[idx] = cv;
    float hv = sigm(go) * tanhf(cv);
    ushort_t hh, ll; split2(hv, hh, ll);
    h_hi[(size_t)n * 192 + e] = hh;
    h_lo[(size_t)n * 192 + e] = ll;
}

// leaf inputs (bf16 pair): row r = (j*256+b)*8 + t  <-  embed row b*64+8j+t
__global__ void gather_leaf_bf(const ushort_t* __restrict__ ehi, const ushort_t* __restrict__ elo,
                               ushort_t* __restrict__ xhi, ushort_t* __restrict__ xlo)
{
    int idx = blockIdx.x * blockDim.x + threadIdx.x;
    if (idx >= 12288 * 192) return;
    int r = idx / 192, e = idx - r * 192;
    int t = r & 7, nb = r >> 3;
    int b = nb & 255, j = nb >> 8;
    int s = (b * 64 + 8 * j + t) * 192 + e;
    xhi[idx] = ehi[s];
    xlo[idx] = elo[s];
}

// mid inputs: row r = (i*256+b)*2 + t  <-  leaf_state row (2i+t)*256 + b
__global__ void gather_mid_bf(const ushort_t* __restrict__ shi, const ushort_t* __restrict__ slo,
                              ushort_t* __restrict__ dhi, ushort_t* __restrict__ dlo)
{
    int idx = blockIdx.x * blockDim.x + threadIdx.x;
    if (idx >= 1536 * 192) return;
    int r = idx / 192, e = idx - r * 192;
    int t = r & 1, m = r >> 1;
    int b = m & 255, i = m >> 8;
    int s = ((2 * i + t) * 256 + b) * 192 + e;
    dhi[idx] = shi[s];
    dlo[idx] = slo[s];
}

// root inputs: row r = b*3 + t  <-  mid_state row t*256 + b
__global__ void gather_root_bf(const ushort_t* __restrict__ shi, const ushort_t* __restrict__ slo,
                               ushort_t* __restrict__ dhi, ushort_t* __restrict__ dlo)
{
    int idx = blockIdx.x * blockDim.x + threadIdx.x;
    if (idx >= 768 * 192) return;
    int r = idx / 192, e = idx - r * 192;
    int b = r / 3, t = r - b * 3;
    int s = (t * 256 + b) * 192 + e;
    dhi[idx] = shi[s];
    dlo[idx] = slo[s];
}

__global__ void bias_prep(const float* __restrict__ cl_bih, const float* __restrict__ cl_bhh,
                          const float* __restrict__ nl_bih, const float* __restrict__ nl_bhh,
                          const float* __restrict__ cc_w0, const float* __restrict__ cc_b0,
                          const float* __restrict__ no_nodes, const float* __restrict__ no_comps,
                          float* __restrict__ clb, float* __restrict__ nlb,
                          float* __restrict__ b1, float* __restrict__ b2)
{
    int tid = blockIdx.x * blockDim.x + threadIdx.x;
    if (tid < 720) {
        clb[tid] = cl_bih[tid] + cl_bhh[tid];
    } else if (tid < 1440) {
        int o = tid - 720;
        nlb[o] = nl_bih[o] + nl_bhh[o];
    } else if (tid < 1640) {
        int o = tid - 1440;
        float s = cc_b0[o];
        for (int e = 0; e < 180; ++e) s = fmaf(no_nodes[e], cc_w0[o * 360 + e], s);
        b1[o] = s;   // leaf: nodes half is constant no_nodes (cols 0:180)
    } else if (tid < 1840) {
        int o = tid - 1640;
        float s = cc_b0[o];
        for (int e = 0; e < 180; ++e) s = fmaf(no_comps[e], cc_w0[o * 360 + 180 + e], s);
        b2[o] = s;   // interior: comps half is constant no_comps (cols 180:360)
    }
}

__global__ void pred_kernel(const float* __restrict__ x, const float* __restrict__ pw,
                            const float* __restrict__ pb, float* __restrict__ out)
{
    int b = blockIdx.x * blockDim.x + threadIdx.x;
    if (b >= 256) return;
    float s = pb[0];
#pragma unroll 4
    for (int e = 0; e < 180; ++e) s = fmaf(x[b * 180 + e], pw[e], s);
    out[b] = s;
}

extern "C" void kernel_launch(void* const* d_in, const int* in_sizes, int n_in,
                              void* d_out, int out_size, void* d_ws, size_t ws_size,
                              hipStream_t stream)
{
    const float* ast    = (const float*)d_in[0];   // 256x64x1024
    const float* ce_w0  = (const float*)d_in[1];   // 600x1024
    const float* ce_b0  = (const float*)d_in[2];
    const float* ce_w1  = (const float*)d_in[3];   // 350x600
    const float* ce_b1  = (const float*)d_in[4];
    const float* ce_w2  = (const float*)d_in[5];   // 200x350
    const float* ce_b2  = (const float*)d_in[6];
    const float* ce_w3  = (const float*)d_in[7];   // 180x200
    const float* ce_b3  = (const float*)d_in[8];
    const float* cc_w0  = (const float*)d_in[9];   // 200x360
    const float* cc_b0  = (const float*)d_in[10];
    const float* cc_w1  = (const float*)d_in[11];  // 180x200
    const float* cc_b1  = (const float*)d_in[12];
    const float* rg_w0  = (const float*)d_in[13];  // 200x180
    const float* rg_b0  = (const float*)d_in[14];
    const float* rg_w1  = (const float*)d_in[15];  // 180x200
    const float* rg_b1  = (const float*)d_in[16];
    const float* pred_w = (const float*)d_in[17];  // 1x180
    const float* pred_b = (const float*)d_in[18];
    const float* cl_Wih = (const float*)d_in[19];  // 720x180
    const float* cl_Whh = (const float*)d_in[20];
    const float* cl_bih = (const float*)d_in[21];
    const float* cl_bhh = (const float*)d_in[22];
    const float* nl_Wih = (const float*)d_in[23];
    const float* nl_Whh = (const float*)d_in[24];
    const float* nl_bih = (const float*)d_in[25];
    const float* nl_bhh = (const float*)d_in[26];
    const float* no_comps = (const float*)d_in[27]; // 1x180
    const float* no_nodes = (const float*)d_in[28]; // 1x180
    float* out = (float*)d_out;                     // 256 f32

    char* ws = (char*)d_ws;

    // ---- workspace layout (identical to R6) ----
    const size_t Z1SZ = 39845888;   // A1 pair region
    const size_t WTSZ = 7560192;
    const bool pre = ws_size >= (size_t)67108864 + Z1SZ + WTSZ + 8192;
    const size_t z0sz = pre ? 67108864 : 35651584;

    char* Z0 = ws;
    char* Z1 = ws + z0sz;
    char* WT = Z1 + Z1SZ;
    char* BI = WT + WTSZ;

    ushort_t* A0hi = (ushort_t*)Z0;                       // 16384x1024 (PRE only)
    ushort_t* A0lo = (ushort_t*)(Z0 + 33554432);
    ushort_t* A2hi = (ushort_t*)Z0;                       // 16384x352
    ushort_t* A2lo = (ushort_t*)(Z0 + 11534336);
    ushort_t* EMhi = (ushort_t*)Z0;                       // embed 16384x192
    ushort_t* EMlo = (ushort_t*)(Z0 + 6291456);
    float*    XWl  = (float*)Z0;                          // 12288x720 f32

    ushort_t* A1hi = (ushort_t*)Z1;                       // 16384x608
    ushort_t* A1lo = (ushort_t*)(Z1 + 19922944);
    ushort_t* A3hi = (ushort_t*)Z1;                       // 16384x224
    ushort_t* A3lo = (ushort_t*)(Z1 + 7340032);
    ushort_t* XGhi = (ushort_t*)Z1;                       // Xg 12288x192
    ushort_t* XGlo = (ushort_t*)(Z1 + 4718592);
    char* S = Z1 + 9437184;                               // smalls (~20.4 MB)

    ushort_t* hl_hi = (ushort_t*)(S);                     // 1536x192
    ushort_t* hl_lo = (ushort_t*)(S + 589824);
    float*    c_l   = (float*)(S + 1179648);              // 1536x180
    float*    G     = (float*)(S + 2285568);              // up to 1536x720
    ushort_t* ls_hi = (ushort_t*)(S + 6709248);           // leaf_state 1536x192
    ushort_t* ls_lo = (ushort_t*)(S + 7299072);
    ushort_t* y2_hi = (ushort_t*)(S + 7888896);           // y200 1536x224
    ushort_t* y2_lo = (ushort_t*)(S + 8577024);
    ushort_t* x2_hi = (ushort_t*)(S + 9265152);           // Xg2 1536x192
    ushort_t* x2_lo = (ushort_t*)(S + 9854976);
    float*    XW2   = (float*)(S + 10444800);             // 1536x720
    ushort_t* hm_hi = (ushort_t*)(S + 14868480);          // 768x192
    ushort_t* hm_lo = (ushort_t*)(S + 15163392);
    float*    c_m   = (float*)(S + 15458304);             // 768x180
    ushort_t* ms_hi = (ushort_t*)(S + 16011264);          // mid_state 768x192
    ushort_t* ms_lo = (ushort_t*)(S + 16306176);
    ushort_t* x3_hi = (ushort_t*)(S + 16601088);          // Xg3 768x192
    ushort_t* x3_lo = (ushort_t*)(S + 16896000);
    float*    XW3   = (float*)(S + 17190912);             // 768x720
    ushort_t* hr_hi = (ushort_t*)(S + 19402752);          // 256x192
    ushort_t* hr_lo = (ushort_t*)(S + 19501056);
    float*    c_r   = (float*)(S + 19599360);             // 256x180
    ushort_t* pg_hi = (ushort_t*)(S + 19783680);          // prog 256x192
    ushort_t* pg_lo = (ushort_t*)(S + 19881984);
    ushort_t* r2_hi = (ushort_t*)(S + 19980288);          // r200 256x224
    ushort_t* r2_lo = (ushort_t*)(S + 20094976);
    float*    r180  = (float*)(S + 20209664);             // 256x180

    // WT tenants (all Rp multiples of 128, Cp multiples of 32)
    ushort_t* w0hi  = (ushort_t*)(WT);                    // 640x1024
    ushort_t* w0lo  = (ushort_t*)(WT + 1310720);
    ushort_t* w1hi  = (ushort_t*)(WT + 2621440);          // 384x608
    ushort_t* w1lo  = (ushort_t*)(WT + 3088384);
    ushort_t* w2hi  = (ushort_t*)(WT + 3555328);          // 256x352
    ushort_t* w2lo  = (ushort_t*)(WT + 3735552);
    ushort_t* w3hi  = (ushort_t*)(WT + 3915776);          // 256x224
    ushort_t* w3lo  = (ushort_t*)(WT + 4030464);
    ushort_t* wiC_h = (ushort_t*)(WT + 4145152);          // cl_Wih 768x192
    ushort_t* wiC_l = (ushort_t*)(WT + 4440064);
    ushort_t* whC_h = (ushort_t*)(WT + 4734976);          // cl_Whh 768x192
    ushort_t* whC_l = (ushort_t*)(WT + 5029888);
    ushort_t* wiN_h = (ushort_t*)(WT + 5324800);          // nl_Wih 768x192
    ushort_t* wiN_l = (ushort_t*)(WT + 5619712);
    ushort_t* whN_h = (ushort_t*)(WT + 5914624);          // nl_Whh 768x192
    ushort_t* whN_l = (ushort_t*)(WT + 6209536);
    ushort_t* c0L_h = (ushort_t*)(WT + 6504448);          // cc_w0 cols 180:360, 256x192
    ushort_t* c0L_l = (ushort_t*)(WT + 6602752);
    ushort_t* c0I_h = (ushort_t*)(WT + 6701056);          // cc_w0 cols 0:180, 256x192
    ushort_t* c0I_l = (ushort_t*)(WT + 6799360);
    ushort_t* c1_h  = (ushort_t*)(WT + 6897664);          // cc_w1 256x224
    ushort_t* c1_l  = (ushort_t*)(WT + 7012352);
    ushort_t* rg0_h = (ushort_t*)(WT + 7127040);          // rg_w0 256x192
    ushort_t* rg0_l = (ushort_t*)(WT + 7225344);
    ushort_t* rg1_h = (ushort_t*)(WT + 7323648);          // rg_w1 256x224
    ushort_t* rg1_l = (ushort_t*)(WT + 7438336);

    float* clb = (float*)BI;
    float* nlb = (float*)(BI + 2880);
    float* b1  = (float*)(BI + 5760);
    float* b2  = (float*)(BI + 6560);

    // ---- 0. conversions + folded biases ----
    if (pre)
        conv_a0<<<16384, 256, 0, stream>>>(ast, A0hi, A0lo);
    conv_w<<<(640*1024 + 255)/256, 256, 0, stream>>>(ce_w0, 1024, 0, 600, 1024, w0hi, w0lo, 640, 1024);
    conv_w<<<(384*608 + 255)/256, 256, 0, stream>>>(ce_w1, 600, 0, 350, 600, w1hi, w1lo, 384, 608);
    conv_w<<<(256*352 + 255)/256, 256, 0, stream>>>(ce_w2, 350, 0, 200, 350, w2hi, w2lo, 256, 352);
    conv_w<<<(256*224 + 255)/256, 256, 0, stream>>>(ce_w3, 200, 0, 180, 200, w3hi, w3lo, 256, 224);
    conv_w<<<(768*192 + 255)/256, 256, 0, stream>>>(cl_Wih, 180, 0, 720, 180, wiC_h, wiC_l, 768, 192);
    conv_w<<<(768*192 + 255)/256, 256, 0, stream>>>(cl_Whh, 180, 0, 720, 180, whC_h, whC_l, 768, 192);
    conv_w<<<(768*192 + 255)/256, 256, 0, stream>>>(nl_Wih, 180, 0, 720, 180, wiN_h, wiN_l, 768, 192);
    conv_w<<<(768*192 + 255)/256, 256, 0, stream>>>(nl_Whh, 180, 0, 720, 180, whN_h, whN_l, 768, 192);
    conv_w<<<(256*192 + 255)/256, 256, 0, stream>>>(cc_w0, 360, 180, 200, 180, c0L_h, c0L_l, 256, 192);
    conv_w<<<(256*192 + 255)/256, 256, 0, stream>>>(cc_w0, 360, 0, 200, 180, c0I_h, c0I_l, 256, 192);
    conv_w<<<(256*224 + 255)/256, 256, 0, stream>>>(cc_w1, 200, 0, 180, 200, c1_h, c1_l, 256, 224);
    conv_w<<<(256*192 + 255)/256, 256, 0, stream>>>(rg_w0, 180, 0, 200, 180, rg0_h, rg0_l, 256, 192);
    conv_w<<<(256*224 + 255)/256, 256, 0, stream>>>(rg_w1, 200, 0, 180, 200, rg1_h, rg1_l, 256, 224);
    bias_prep<<<(1840 + 255)/256, 256, 0, stream>>>(
        cl_bih, cl_bhh, nl_bih, nl_bhh, cc_w0, cc_b0, no_nodes, no_comps,
        clb, nlb, b1, b2);

    dim3 blk(256);

    // ---- 1. comp-embedding MLP (ELU fused, bf16-pair epilogue) ----
    if (pre)
        gemm_lds<true><<<dim3(5, 128), blk, 0, stream>>>(
            A0hi, A0lo, 1024, w0hi, w0lo, 1024, ce_b0,
            nullptr, A1hi, A1lo, 608, 600, 1024, 1);
    else
        gemm_mfma_f32a<<<dim3(5, 128), blk, 0, stream>>>(
            ast, 1024, w0hi, w0lo, 1024, ce_b0,
            A1hi, A1lo, 608, 600, 1024, 1);
    gemm_lds<true><<<dim3(3, 128), blk, 0, stream>>>(
        A1hi, A1lo, 608, w1hi, w1lo, 608, ce_b1,
        nullptr, A2hi, A2lo, 352, 350, 608, 1);
    gemm_lds<true><<<dim3(2, 128), blk, 0, stream>>>(
        A2hi, A2lo, 352, w2hi, w2lo, 352, ce_b2,
        nullptr, A3hi, A3lo, 224, 200, 352, 1);
    gemm_lds<true><<<dim3(2, 128), blk, 0, stream>>>(
        A3hi, A3lo, 224, w3hi, w3lo, 224, ce_b3,
        nullptr, EMhi, EMlo, 192, 180, 224, 1);

    // ---- 2. leaf LSTM: batch 1536 (6 leaves x 256), T=8 ----
    gather_leaf_bf<<<(12288*192 + 255)/256, 256, 0, stream>>>(EMhi, EMlo, XGhi, XGlo);
    gemm_lds<false><<<dim3(6, 96), blk, 0, stream>>>(
        XGhi, XGlo, 192, wiC_h, wiC_l, 192, clb,
        XWl, nullptr, nullptr, 0, 720, 192, 0);
    hipMemsetAsync(S, 0, 2285568, stream);  // hl pair + c_l
    for (int t = 0; t < 8; ++t) {
        if (t > 0)
            gemm_lds<false><<<dim3(6, 12), blk, 0, stream>>>(
                hl_hi, hl_lo, 192, whC_h, whC_l, 192, nullptr,
                G, nullptr, nullptr, 0, 720, 192, 0);
        lstm_gate<<<(1536*180 + 255)/256, 256, 0, stream>>>(
            hl_hi, hl_lo, c_l, t ? G : nullptr, XWl, 1536, 8, t);
    }
    // leaf concat: comps half of cc_w0, no_nodes folded in b1
    gemm_lds<true><<<dim3(2, 12), blk, 0, stream>>>(
        hl_hi, hl_lo, 192, c0L_h, c0L_l, 192, b1,
        nullptr, y2_hi, y2_lo, 224, 200, 192, 1);
    gemm_lds<true><<<dim3(2, 12), blk, 0, stream>>>(
        y2_hi, y2_lo, 224, c1_h, c1_l, 224, cc_b1,
        nullptr, ls_hi, ls_lo, 192, 180, 224, 1);

    // ---- 3. mid LSTM: batch 768 (3 mids x 256), T=2 ----
    gather_mid_bf<<<(1536*192 + 255)/256, 256, 0, stream>>>(ls_hi, ls_lo, x2_hi, x2_lo);
    gemm_lds<false><<<dim3(6, 12), blk, 0, stream>>>(
        x2_hi, x2_lo, 192, wiN_h, wiN_l, 192, nlb,
        XW2, nullptr, nullptr, 0, 720, 192, 0);
    hipMemsetAsync(S + 14868480, 0, 1142784, stream);  // hm pair + c_m
    for (int t = 0; t < 2; ++t) {
        if (t > 0)
            gemm_lds<false><<<dim3(6, 6), blk, 0, stream>>>(
                hm_hi, hm_lo, 192, whN_h, whN_l, 192, nullptr,
                G, nullptr, nullptr, 0, 720, 192, 0);
        lstm_gate<<<(768*180 + 255)/256, 256, 0, stream>>>(
            hm_hi, hm_lo, c_m, t ? G : nullptr, XW2, 768, 2, t);
    }
    // interior concat: nodes half of cc_w0, no_comps folded in b2
    gemm_lds<true><<<dim3(2, 6), blk, 0, stream>>>(
        hm_hi, hm_lo, 192, c0I_h, c0I_l, 192, b2,
        nullptr, y2_hi, y2_lo, 224, 200, 192, 1);
    gemm_lds<true><<<dim3(2, 6), blk, 0, stream>>>(
        y2_hi, y2_lo, 224, c1_h, c1_l, 224, cc_b1,
        nullptr, ms_hi, ms_lo, 192, 180, 224, 1);

    // ---- 4. root LSTM: batch 256, T=3 ----
    gather_root_bf<<<(768*192 + 255)/256, 256, 0, stream>>>(ms_hi, ms_lo, x3_hi, x3_lo);
    gemm_lds<false><<<dim3(6, 6), blk, 0, stream>>>(
        x3_hi, x3_lo, 192, wiN_h, wiN_l, 192, nlb,
        XW3, nullptr, nullptr, 0, 720, 192, 0);
    hipMemsetAsync(S + 19402752, 0, 380928, stream);  // hr pair + c_r
    for (int t = 0; t < 3; ++t) {
        if (t > 0)
            gemm_lds<false><<<dim3(6, 2), blk, 0, stream>>>(
                hr_hi, hr_lo, 192, whN_h, whN_l, 192, nullptr,
                G, nullptr, nullptr, 0, 720, 192, 0);
        lstm_gate<<<(256*180 + 255)/256, 256, 0, stream>>>(
            hr_hi, hr_lo, c_r, t ? G : nullptr, XW3, 256, 3, t);
    }
    gemm_lds<true><<<dim3(2, 2), blk, 0, stream>>>(
        hr_hi, hr_lo, 192, c0I_h, c0I_l, 192, b2,
        nullptr, y2_hi, y2_lo, 224, 200, 192, 1);
    gemm_lds<true><<<dim3(2, 2), blk, 0, stream>>>(
        y2_hi, y2_lo, 224, c1_h, c1_l, 224, cc_b1,
        nullptr, pg_hi, pg_lo, 192, 180, 224, 1);

    // ---- 5. regression + prediction ----
    gemm_lds<true><<<dim3(2, 2), blk, 0, stream>>>(
        pg_hi, pg_lo, 192, rg0_h, rg0_l, 192, rg_b0,
        nullptr, r2_hi, r2_lo, 224, 200, 192, 1);
    gemm_lds<false><<<dim3(2, 2), blk, 0, stream>>>(
        r2_hi, r2_lo, 224, rg1_h, rg1_l, 224, rg_b1,
        r180, nullptr, nullptr, 0, 180, 224, 1);
    pred_kernel<<<1, 256, 0, stream>>>(r180, pred_w, pred_b, out);
}

// Round 8
// 996.836 us; speedup vs baseline: 1.3074x; 1.0693x over previous
//
#include <hip/hip_runtime.h>
#include <math.h>

// ---------------------------------------------------------------------------
// Model_Recursive_LSTM_v2 — round 8: 2-phase dbuf pipeline + XCD swizzle +
// merged prep kernel.
//
// R7 counters: L0 = 135us, MfmaUtil 19.6%, VALUBusy 20.9%, Occupancy 22%,
// FETCH 202MB (A re-fetched ~3x across XCDs), bank conflicts 0.
// Changes:
//   1. gemm_lds: double-buffered LDS (2 x 32KB dynamic), prefetch next K-tile
//      BEFORE compute, ONE __syncthreads per K-step (its vmcnt(0) drain lands
//      after the MFMAs -> load latency hidden under compute). T3-min recipe.
//   2. Bijective XCD swizzle (T1) when nwg%8==0: each XCD gets a contiguous
//      run of logical tiles -> A row-panels fetched by one XCD's L2 only.
//   3. prep_all: 13 conv_w + bias_prep + 3 state-zeroes merged into ONE
//      range-dispatched kernel (stream serializes everything; fewer launches).
// Numerics unchanged: split-bf16 (hh+hl+lh, f32 accum), absmax 6.1e-5 in R7.
// ---------------------------------------------------------------------------

typedef __attribute__((ext_vector_type(8))) short bf16x8;
typedef __attribute__((ext_vector_type(4))) float f32x4;
typedef __attribute__((ext_vector_type(4))) unsigned short us4;
typedef unsigned short ushort_t;
typedef unsigned int uint_t;

__device__ __forceinline__ float elu1(float x) { return x > 0.f ? x : expm1f(x); }
__device__ __forceinline__ float sigm(float x) { return 1.f / (1.f + expf(-x)); }

__device__ __forceinline__ ushort_t f2bf(float f) {
    union { float f; uint_t u; } v; v.f = f;
    uint_t u = v.u;
    uint_t r = u + 0x7FFFu + ((u >> 16) & 1u);   // round-to-nearest-even
    return (ushort_t)(r >> 16);
}
__device__ __forceinline__ float bf2f(ushort_t h) {
    union { uint_t u; float f; } v; v.u = ((uint_t)h) << 16;
    return v.f;
}
__device__ __forceinline__ void split2(float x, ushort_t& hi, ushort_t& lo) {
    ushort_t h = f2bf(x);
    hi = h;
    lo = f2bf(x - bf2f(h));
}

__device__ __forceinline__ bf16x8 ld8(const ushort_t* p) { return *(const bf16x8*)p; }

__device__ __forceinline__ void load_split_f32(const float* p, bf16x8& h8, bf16x8& l8) {
    const float4* q = (const float4*)p;
    float4 a = q[0], b = q[1];
    float v[8] = {a.x, a.y, a.z, a.w, b.x, b.y, b.z, b.w};
#pragma unroll
    for (int i = 0; i < 8; ++i) {
        ushort_t h, l; split2(v[i], h, l);
        h8[i] = (short)h; l8[i] = (short)l;
    }
}

// async global -> LDS, 16 B per lane (lands at lds_base + lane*16)
__device__ __forceinline__ void gload16(const void* g, void* l) {
    __builtin_amdgcn_global_load_lds(
        (const __attribute__((address_space(1))) unsigned int*)g,
        (__attribute__((address_space(3))) unsigned int*)l,
        16, 0, 0);
}

// ---------------------------------------------------------------------------
// Double-buffered LDS-staged split-bf16 GEMM. C = act(A * W^T + bias).
// A: bf16 hi/lo planes, (grid.y*128) x lda.  W: bf16 hi/lo planes,
// (grid.x*128) x ldw (zero-padded). Kp % 32 == 0. Dynamic LDS = 65536 B.
// OUTPAIR: bf16 hi/lo planes M x ldc (cols in [N,ldc) zeroed); else f32 M x N.
// ---------------------------------------------------------------------------
template <bool OUTPAIR>
__global__ __launch_bounds__(256)
void gemm_lds(const ushort_t* __restrict__ Ahi, const ushort_t* __restrict__ Alo, int lda,
              const ushort_t* __restrict__ Whi, const ushort_t* __restrict__ Wlo, int ldw,
              const float* __restrict__ bias,
              float* __restrict__ Cf, ushort_t* __restrict__ Chi, ushort_t* __restrict__ Clo,
              int ldc, int N, int Kp, int act)
{
    extern __shared__ char smem[];       // 2 bufs x 4 planes x 8192 B = 64 KB
    const int tid  = threadIdx.x;
    const int lane = tid & 63;
    const int wave = tid >> 6;
    const int wm = wave & 1;             // row half of 128x128 tile
    const int wn = wave >> 1;            // col half
    const int j16 = lane & 15;
    const int kq  = lane >> 4;           // k-slot 0..3 (8 bf16 each)

    // T1 bijective XCD swizzle (identity unless nwg % 8 == 0)
    const int gx = gridDim.x;
    const int nwg = gx * gridDim.y;
    int wg = blockIdx.y * gx + blockIdx.x;
    if ((nwg & 7) == 0) {
        const int cpx = nwg >> 3;
        wg = (wg & 7) * cpx + (wg >> 3);
    }
    const int bm = (wg / gx) * 128;
    const int bn = (wg % gx) * 128;

    // staging role: wave p stages plane p (0=Ahi,1=Alo,2=Whi,3=Wlo)
    const ushort_t* sbase = (wave == 0) ? Ahi : (wave == 1) ? Alo
                          : (wave == 2) ? Whi : Wlo;
    const int srow0 = (wave < 2) ? bm : bn;
    const int sld   = (wave < 2) ? lda : ldw;
    const size_t soff = (size_t)(srow0 + j16) * sld + kq * 8;
    const int lp = wave * 8192;          // this wave's plane offset

    f32x4 acc[4][4] = {};

    // prologue: stage k-tile 0 into buffer 0
#pragma unroll
    for (int u = 0; u < 8; ++u)
        gload16(sbase + soff + (size_t)u * 16 * sld, smem + lp + u * 1024);
    __syncthreads();

    int cur = 0;
    for (int k0 = 0; k0 < Kp; k0 += 32) {
        if (k0 + 32 < Kp) {              // prefetch next tile into other buffer
            char* nb = smem + ((cur ^ 1) << 15) + lp;
#pragma unroll
            for (int u = 0; u < 8; ++u)
                gload16(sbase + soff + (size_t)u * 16 * sld + k0 + 32, nb + u * 1024);
        }
        const char* cb = smem + (cur << 15);
        bf16x8 ah[4], al[4], bh[4], bl[4];
#pragma unroll
        for (int i = 0; i < 4; ++i) {
            const int ta = (wm * 4 + i) * 1024 + lane * 16;
            const int tb = (wn * 4 + i) * 1024 + lane * 16;
            ah[i] = *(const bf16x8*)(cb +         ta);
            al[i] = *(const bf16x8*)(cb +  8192 + ta);
            bh[i] = *(const bf16x8*)(cb + 16384 + tb);
            bl[i] = *(const bf16x8*)(cb + 24576 + tb);
        }
#pragma unroll
        for (int ms = 0; ms < 4; ++ms)
#pragma unroll
        for (int ns = 0; ns < 4; ++ns) {
            acc[ms][ns] = __builtin_amdgcn_mfma_f32_16x16x32_bf16(ah[ms], bh[ns], acc[ms][ns], 0, 0, 0);
            acc[ms][ns] = __builtin_amdgcn_mfma_f32_16x16x32_bf16(ah[ms], bl[ns], acc[ms][ns], 0, 0, 0);
            acc[ms][ns] = __builtin_amdgcn_mfma_f32_16x16x32_bf16(al[ms], bh[ns], acc[ms][ns], 0, 0, 0);
        }
        __syncthreads();                 // vmcnt(0) drain lands AFTER compute
        cur ^= 1;
    }

    const int rbase = kq << 2;           // D row base: 0,4,8,12
#pragma unroll
    for (int ms = 0; ms < 4; ++ms)
#pragma unroll
    for (int ns = 0; ns < 4; ++ns) {
        const int gc = bn + wn * 64 + ns * 16 + j16;
#pragma unroll
        for (int r = 0; r < 4; ++r) {
            const int gr = bm + wm * 64 + ms * 16 + rbase + r;
            float v = acc[ms][ns][r];
            if constexpr (OUTPAIR) {
                if (gc < ldc) {
                    float o = 0.f;
                    if (gc < N) {
                        o = v + (bias ? bias[gc] : 0.f);
                        if (act) o = elu1(o);
                    }
                    ushort_t hh, ll; split2(o, hh, ll);
                    Chi[(size_t)gr * ldc + gc] = hh;
                    Clo[(size_t)gr * ldc + gc] = ll;
                }
            } else {
                if (gc < N) {
                    float o = v + (bias ? bias[gc] : 0.f);
                    if (act) o = elu1(o);
                    Cf[(size_t)gr * N + gc] = o;
                }
            }
        }
    }
}

// ---------------------------------------------------------------------------
// Fallback L0 kernel (in-register split from f32 A) for small-ws deployments.
// ---------------------------------------------------------------------------
__global__ __launch_bounds__(256)
void gemm_mfma_f32a(const float* __restrict__ A, int lda,
                    const ushort_t* __restrict__ Whi, const ushort_t* __restrict__ Wlo, int ldw,
                    const float* __restrict__ bias,
                    ushort_t* __restrict__ Chi, ushort_t* __restrict__ Clo,
                    int ldc, int N, int Kp, int act)
{
    const int lane = threadIdx.x & 63;
    const int wave = threadIdx.x >> 6;
    const int wm = wave & 1, wn = wave >> 1;
    const int r16 = lane & 15;
    const int kb  = (lane >> 4) << 3;
    const int bm = blockIdx.y * 128 + wm * 64;
    const int bn = blockIdx.x * 128 + wn * 64;

    f32x4 acc[4][4] = {};
    size_t aoff[4];
    const ushort_t *wh[4], *wl[4];
#pragma unroll
    for (int i = 0; i < 4; ++i) {
        aoff[i] = (size_t)(bm + i * 16 + r16) * lda + kb;
        wh[i] = Whi + (size_t)(bn + i * 16 + r16) * ldw + kb;
        wl[i] = Wlo + (size_t)(bn + i * 16 + r16) * ldw + kb;
    }
    for (int k = 0; k < Kp; k += 32) {
        bf16x8 ah[4], al[4], bh[4], bl[4];
#pragma unroll
        for (int i = 0; i < 4; ++i) {
            load_split_f32(A + aoff[i] + k, ah[i], al[i]);
            bh[i] = ld8(wh[i] + k);
            bl[i] = ld8(wl[i] + k);
        }
#pragma unroll
        for (int ms = 0; ms < 4; ++ms)
#pragma unroll
        for (int ns = 0; ns < 4; ++ns) {
            acc[ms][ns] = __builtin_amdgcn_mfma_f32_16x16x32_bf16(ah[ms], bh[ns], acc[ms][ns], 0, 0, 0);
            acc[ms][ns] = __builtin_amdgcn_mfma_f32_16x16x32_bf16(ah[ms], bl[ns], acc[ms][ns], 0, 0, 0);
            acc[ms][ns] = __builtin_amdgcn_mfma_f32_16x16x32_bf16(al[ms], bh[ns], acc[ms][ns], 0, 0, 0);
        }
    }
    const int rbase = (lane >> 4) << 2;
#pragma unroll
    for (int ms = 0; ms < 4; ++ms)
#pragma unroll
    for (int ns = 0; ns < 4; ++ns) {
        const int gc = bn + ns * 16 + r16;
#pragma unroll
        for (int r = 0; r < 4; ++r) {
            const int gr = bm + ms * 16 + rbase + r;
            if (gc < ldc) {
                float o = 0.f;
                if (gc < N) {
                    o = acc[ms][ns][r] + bias[gc];
                    if (act) o = elu1(o);
                }
                ushort_t hh, ll; split2(o, hh, ll);
                Chi[(size_t)gr * ldc + gc] = hh;
                Clo[(size_t)gr * ldc + gc] = ll;
            }
        }
    }
}

// Pre-split ast (16384x1024 f32) into bf16 hi/lo planes, float4-vectorized.
__global__ void conv_a0(const float* __restrict__ src, ushort_t* __restrict__ dhi,
                        ushort_t* __restrict__ dlo)
{
    int idx = blockIdx.x * blockDim.x + threadIdx.x;
    if (idx >= 16384 * 256) return;
    float4 v = ((const float4*)src)[idx];
    float x[4] = {v.x, v.y, v.z, v.w};
    us4 h, l;
#pragma unroll
    for (int i = 0; i < 4; ++i) {
        ushort_t hh, ll; split2(x[i], hh, ll);
        h[i] = hh; l[i] = ll;
    }
    ((us4*)dhi)[idx] = h;
    ((us4*)dlo)[idx] = l;
}

// ---------------------------------------------------------------------------
// prep_all: 13 weight conversions + folded biases + state zeroing, one kernel.
// Flat index ranges (constants must match the ws layout in kernel_launch).
// ---------------------------------------------------------------------------
__device__ __forceinline__ bool do_conv(int idx, int base, int cnt, int Cp,
    const float* __restrict__ src, int sld, int soff, int R, int C,
    ushort_t* __restrict__ dhi, ushort_t* __restrict__ dlo)
{
    if (idx >= base + cnt) return false;
    int k = idx - base;
    int r = k / Cp, c = k - r * Cp;
    float v = (r < R && c < C) ? src[r * sld + soff + c] : 0.f;
    ushort_t h, l; split2(v, h, l);
    dhi[k] = h; dlo[k] = l;
    return true;
}

__global__ void prep_all(
    const float* __restrict__ ce_w0, const float* __restrict__ ce_w1,
    const float* __restrict__ ce_w2, const float* __restrict__ ce_w3,
    const float* __restrict__ cl_Wih, const float* __restrict__ cl_Whh,
    const float* __restrict__ nl_Wih, const float* __restrict__ nl_Whh,
    const float* __restrict__ cc_w0, const float* __restrict__ cc_w1,
    const float* __restrict__ rg_w0, const float* __restrict__ rg_w1,
    const float* __restrict__ cl_bih, const float* __restrict__ cl_bhh,
    const float* __restrict__ nl_bih, const float* __restrict__ nl_bhh,
    const float* __restrict__ cc_b0,
    const float* __restrict__ no_nodes, const float* __restrict__ no_comps,
    ushort_t* w0hi, ushort_t* w0lo, ushort_t* w1hi, ushort_t* w1lo,
    ushort_t* w2hi, ushort_t* w2lo, ushort_t* w3hi, ushort_t* w3lo,
    ushort_t* wiC_h, ushort_t* wiC_l, ushort_t* whC_h, ushort_t* whC_l,
    ushort_t* wiN_h, ushort_t* wiN_l, ushort_t* whN_h, ushort_t* whN_l,
    ushort_t* c0L_h, ushort_t* c0L_l, ushort_t* c0I_h, ushort_t* c0I_l,
    ushort_t* c1_h, ushort_t* c1_l, ushort_t* rg0_h, ushort_t* rg0_l,
    ushort_t* rg1_h, ushort_t* rg1_l,
    float* clb, float* nlb, float* b1, float* b2,
    char* S)
{
    int idx = blockIdx.x * blockDim.x + threadIdx.x;
    if (do_conv(idx,       0, 655360, 1024, ce_w0, 1024, 0, 600, 1024, w0hi, w0lo)) return;
    if (do_conv(idx,  655360, 233472,  608, ce_w1,  600, 0, 350,  600, w1hi, w1lo)) return;
    if (do_conv(idx,  888832,  90112,  352, ce_w2,  350, 0, 200,  350, w2hi, w2lo)) return;
    if (do_conv(idx,  978944,  57344,  224, ce_w3,  200, 0, 180,  200, w3hi, w3lo)) return;
    if (do_conv(idx, 1036288, 147456,  192, cl_Wih, 180, 0, 720,  180, wiC_h, wiC_l)) return;
    if (do_conv(idx, 1183744, 147456,  192, cl_Whh, 180, 0, 720,  180, whC_h, whC_l)) return;
    if (do_conv(idx, 1331200, 147456,  192, nl_Wih, 180, 0, 720,  180, wiN_h, wiN_l)) return;
    if (do_conv(idx, 1478656, 147456,  192, nl_Whh, 180, 0, 720,  180, whN_h, whN_l)) return;
    if (do_conv(idx, 1626112,  49152,  192, cc_w0,  360, 180, 200, 180, c0L_h, c0L_l)) return;
    if (do_conv(idx, 1675264,  49152,  192, cc_w0,  360, 0, 200,  180, c0I_h, c0I_l)) return;
    if (do_conv(idx, 1724416,  57344,  224, cc_w1,  200, 0, 180,  200, c1_h, c1_l)) return;
    if (do_conv(idx, 1781760,  49152,  192, rg_w0,  180, 0, 200,  180, rg0_h, rg0_l)) return;
    if (do_conv(idx, 1830912,  57344,  224, rg_w1,  200, 0, 180,  200, rg1_h, rg1_l)) return;
    if (idx < 1890096) {                       // folded biases (1840 lanes)
        int tid = idx - 1888256;
        if (tid < 720) {
            clb[tid] = cl_bih[tid] + cl_bhh[tid];
        } else if (tid < 1440) {
            int o = tid - 720;
            nlb[o] = nl_bih[o] + nl_bhh[o];
        } else if (tid < 1640) {
            int o = tid - 1440;
            float s = cc_b0[o];
            for (int e = 0; e < 180; ++e) s = fmaf(no_nodes[e], cc_w0[o * 360 + e], s);
            b1[o] = s;
        } else if (tid < 1840) {
            int o = tid - 1640;
            float s = cc_b0[o];
            for (int e = 0; e < 180; ++e) s = fmaf(no_comps[e], cc_w0[o * 360 + 180 + e], s);
            b2[o] = s;
        }
        return;
    }
    // state zeroing (float4 stores): hl/c_l, hm/c_m, hr/c_r regions
    float4 z = make_float4(0.f, 0.f, 0.f, 0.f);
    if (idx < 2032944) { ((float4*)(S))[idx - 1890096] = z; return; }            // 2,285,568 B
    if (idx < 2104368) { ((float4*)(S + 14868480))[idx - 2032944] = z; return; } // 1,142,784 B
    if (idx < 2128176) { ((float4*)(S + 19402752))[idx - 2104368] = z; return; } //   380,928 B
}

// Gate update. G (rows x 720 f32, nullptr for t=0 where h=0), XW rows
// interleaved by T. Writes c (rows x 180 f32) and h as bf16 hi/lo pair
// (rows x 192; pad cols pre-zeroed).
__global__ void lstm_gate(ushort_t* __restrict__ h_hi, ushort_t* __restrict__ h_lo,
                          float* __restrict__ c,
                          const float* __restrict__ G, const float* __restrict__ XW,
                          int rows, int T, int t)
{
    int idx = blockIdx.x * blockDim.x + threadIdx.x;
    if (idx >= rows * 180) return;
    int n = idx / 180, e = idx - n * 180;
    const float* xw = XW + ((size_t)n * T + t) * 720;
    float gi = xw[e], gf = xw[e + 180], gg = xw[e + 360], go = xw[e + 540];
    if (G) {
        const float* g = G + (size_t)n * 720;
        gi += g[e]; gf += g[e + 180]; gg += g[e + 360]; go += g[e + 540];
    }
    float cv = sigm(gf) * c[idx] + sigm(gi) * tanhf(gg);
    c[idx] = cv;
    float hv = sigm(go) * tanhf(cv);
    ushort_t hh, ll; split2(hv, hh, ll);
    h_hi[(size_t)n * 192 + e] = hh;
    h_lo[(size_t)n * 192 + e] = ll;
}

// leaf inputs (bf16 pair): row r = (j*256+b)*8 + t  <-  embed row b*64+8j+t
__global__ void gather_leaf_bf(const ushort_t* __restrict__ ehi, const ushort_t* __restrict__ elo,
                               ushort_t* __restrict__ xhi, ushort_t* __restrict__ xlo)
{
    int idx = blockIdx.x * blockDim.x + threadIdx.x;
    if (idx >= 12288 * 192) return;
    int r = idx / 192, e = idx - r * 192;
    int t = r & 7, nb = r >> 3;
    int b = nb & 255, j = nb >> 8;
    int s = (b * 64 + 8 * j + t) * 192 + e;
    xhi[idx] = ehi[s];
    xlo[idx] = elo[s];
}

// mid inputs: row r = (i*256+b)*2 + t  <-  leaf_state row (2i+t)*256 + b
__global__ void gather_mid_bf(const ushort_t* __restrict__ shi, const ushort_t* __restrict__ slo,
                              ushort_t* __restrict__ dhi, ushort_t* __restrict__ dlo)
{
    int idx = blockIdx.x * blockDim.x + threadIdx.x;
    if (idx >= 1536 * 192) return;
    int r = idx / 192, e = idx - r * 192;
    int t = r & 1, m = r >> 1;
    int b = m & 255, i = m >> 8;
    int s = ((2 * i + t) * 256 + b) * 192 + e;
    dhi[idx] = shi[s];
    dlo[idx] = slo[s];
}

// root inputs: row r = b*3 + t  <-  mid_state row t*256 + b
__global__ void gather_root_bf(const ushort_t* __restrict__ shi, const ushort_t* __restrict__ slo,
                               ushort_t* __restrict__ dhi, ushort_t* __restrict__ dlo)
{
    int idx = blockIdx.x * blockDim.x + threadIdx.x;
    if (idx >= 768 * 192) return;
    int r = idx / 192, e = idx - r * 192;
    int b = r / 3, t = r - b * 3;
    int s = (t * 256 + b) * 192 + e;
    dhi[idx] = shi[s];
    dlo[idx] = slo[s];
}

__global__ void pred_kernel(const float* __restrict__ x, const float* __restrict__ pw,
                            const float* __restrict__ pb, float* __restrict__ out)
{
    int b = blockIdx.x * blockDim.x + threadIdx.x;
    if (b >= 256) return;
    float s = pb[0];
#pragma unroll 4
    for (int e = 0; e < 180; ++e) s = fmaf(x[b * 180 + e], pw[e], s);
    out[b] = s;
}

extern "C" void kernel_launch(void* const* d_in, const int* in_sizes, int n_in,
                              void* d_out, int out_size, void* d_ws, size_t ws_size,
                              hipStream_t stream)
{
    const float* ast    = (const float*)d_in[0];   // 256x64x1024
    const float* ce_w0  = (const float*)d_in[1];   // 600x1024
    const float* ce_b0  = (const float*)d_in[2];
    const float* ce_w1  = (const float*)d_in[3];   // 350x600
    const float* ce_b1  = (const float*)d_in[4];
    const float* ce_w2  = (const float*)d_in[5];   // 200x350
    const float* ce_b2  = (const float*)d_in[6];
    const float* ce_w3  = (const float*)d_in[7];   // 180x200
    const float* ce_b3  = (const float*)d_in[8];
    const float* cc_w0  = (const float*)d_in[9];   // 200x360
    const float* cc_b0  = (const float*)d_in[10];
    const float* cc_w1  = (const float*)d_in[11];  // 180x200
    const float* cc_b1  = (const float*)d_in[12];
    const float* rg_w0  = (const float*)d_in[13];  // 200x180
    const float* rg_b0  = (const float*)d_in[14];
    const float* rg_w1  = (const float*)d_in[15];  // 180x200
    const float* rg_b1  = (const float*)d_in[16];
    const float* pred_w = (const float*)d_in[17];  // 1x180
    const float* pred_b = (const float*)d_in[18];
    const float* cl_Wih = (const float*)d_in[19];  // 720x180
    const float* cl_Whh = (const float*)d_in[20];
    const float* cl_bih = (const float*)d_in[21];
    const float* cl_bhh = (const float*)d_in[22];
    const float* nl_Wih = (const float*)d_in[23];
    const float* nl_Whh = (const float*)d_in[24];
    const float* nl_bih = (const float*)d_in[25];
    const float* nl_bhh = (const float*)d_in[26];
    const float* no_comps = (const float*)d_in[27]; // 1x180
    const float* no_nodes = (const float*)d_in[28]; // 1x180
    float* out = (float*)d_out;                     // 256 f32

    char* ws = (char*)d_ws;

    // ---- workspace layout (identical to R6/R7) ----
    const size_t Z1SZ = 39845888;   // A1 pair region
    const size_t WTSZ = 7560192;
    const bool pre = ws_size >= (size_t)67108864 + Z1SZ + WTSZ + 8192;
    const size_t z0sz = pre ? 67108864 : 35651584;

    char* Z0 = ws;
    char* Z1 = ws + z0sz;
    char* WT = Z1 + Z1SZ;
    char* BI = WT + WTSZ;

    ushort_t* A0hi = (ushort_t*)Z0;                       // 16384x1024 (PRE only)
    ushort_t* A0lo = (ushort_t*)(Z0 + 33554432);
    ushort_t* A2hi = (ushort_t*)Z0;                       // 16384x352
    ushort_t* A2lo = (ushort_t*)(Z0 + 11534336);
    ushort_t* EMhi = (ushort_t*)Z0;                       // embed 16384x192
    ushort_t* EMlo = (ushort_t*)(Z0 + 6291456);
    float*    XWl  = (float*)Z0;                          // 12288x720 f32

    ushort_t* A1hi = (ushort_t*)Z1;                       // 16384x608
    ushort_t* A1lo = (ushort_t*)(Z1 + 19922944);
    ushort_t* A3hi = (ushort_t*)Z1;                       // 16384x224
    ushort_t* A3lo = (ushort_t*)(Z1 + 7340032);
    ushort_t* XGhi = (ushort_t*)Z1;                       // Xg 12288x192
    ushort_t* XGlo = (ushort_t*)(Z1 + 4718592);
    char* S = Z1 + 9437184;                               // smalls (~20.4 MB)

    ushort_t* hl_hi = (ushort_t*)(S);                     // 1536x192
    ushort_t* hl_lo = (ushort_t*)(S + 589824);
    float*    c_l   = (float*)(S + 1179648);              // 1536x180
    float*    G     = (float*)(S + 2285568);              // up to 1536x720
    ushort_t* ls_hi = (ushort_t*)(S + 6709248);           // leaf_state 1536x192
    ushort_t* ls_lo = (ushort_t*)(S + 7299072);
    ushort_t* y2_hi = (ushort_t*)(S + 7888896);           // y200 1536x224
    ushort_t* y2_lo = (ushort_t*)(S + 8577024);
    ushort_t* x2_hi = (ushort_t*)(S + 9265152);           // Xg2 1536x192
    ushort_t* x2_lo = (ushort_t*)(S + 9854976);
    float*    XW2   = (float*)(S + 10444800);             // 1536x720
    ushort_t* hm_hi = (ushort_t*)(S + 14868480);          // 768x192
    ushort_t* hm_lo = (ushort_t*)(S + 15163392);
    float*    c_m   = (float*)(S + 15458304);             // 768x180
    ushort_t* ms_hi = (ushort_t*)(S + 16011264);          // mid_state 768x192
    ushort_t* ms_lo = (ushort_t*)(S + 16306176);
    ushort_t* x3_hi = (ushort_t*)(S + 16601088);          // Xg3 768x192
    ushort_t* x3_lo = (ushort_t*)(S + 16896000);
    float*    XW3   = (float*)(S + 17190912);             // 768x720
    ushort_t* hr_hi = (ushort_t*)(S + 19402752);          // 256x192
    ushort_t* hr_lo = (ushort_t*)(S + 19501056);
    float*    c_r   = (float*)(S + 19599360);             // 256x180
    ushort_t* pg_hi = (ushort_t*)(S + 19783680);          // prog 256x192
    ushort_t* pg_lo = (ushort_t*)(S + 19881984);
    ushort_t* r2_hi = (ushort_t*)(S + 19980288);          // r200 256x224
    ushort_t* r2_lo = (ushort_t*)(S + 20094976);
    float*    r180  = (float*)(S + 20209664);             // 256x180

    ushort_t* w0hi  = (ushort_t*)(WT);                    // 640x1024
    ushort_t* w0lo  = (ushort_t*)(WT + 1310720);
    ushort_t* w1hi  = (ushort_t*)(WT + 2621440);          // 384x608
    ushort_t* w1lo  = (ushort_t*)(WT + 3088384);
    ushort_t* w2hi  = (ushort_t*)(WT + 3555328);          // 256x352
    ushort_t* w2lo  = (ushort_t*)(WT + 3735552);
    ushort_t* w3hi  = (ushort_t*)(WT + 3915776);          // 256x224
    ushort_t* w3lo  = (ushort_t*)(WT + 4030464);
    ushort_t* wiC_h = (ushort_t*)(WT + 4145152);          // cl_Wih 768x192
    ushort_t* wiC_l = (ushort_t*)(WT + 4440064);
    ushort_t* whC_h = (ushort_t*)(WT + 4734976);          // cl_Whh 768x192
    ushort_t* whC_l = (ushort_t*)(WT + 5029888);
    ushort_t* wiN_h = (ushort_t*)(WT + 5324800);          // nl_Wih 768x192
    ushort_t* wiN_l = (ushort_t*)(WT + 5619712);
    ushort_t* whN_h = (ushort_t*)(WT + 5914624);          // nl_Whh 768x192
    ushort_t* whN_l = (ushort_t*)(WT + 6209536);
    ushort_t* c0L_h = (ushort_t*)(WT + 6504448);          // cc_w0 cols 180:360, 256x192
    ushort_t* c0L_l = (ushort_t*)(WT + 6602752);
    ushort_t* c0I_h = (ushort_t*)(WT + 6701056);          // cc_w0 cols 0:180, 256x192
    ushort_t* c0I_l = (ushort_t*)(WT + 6799360);
    ushort_t* c1_h  = (ushort_t*)(WT + 6897664);          // cc_w1 256x224
    ushort_t* c1_l  = (ushort_t*)(WT + 7012352);
    ushort_t* rg0_h = (ushort_t*)(WT + 7127040);          // rg_w0 256x192
    ushort_t* rg0_l = (ushort_t*)(WT + 7225344);
    ushort_t* rg1_h = (ushort_t*)(WT + 7323648);          // rg_w1 256x224
    ushort_t* rg1_l = (ushort_t*)(WT + 7438336);

    float* clb = (float*)BI;
    float* nlb = (float*)(BI + 2880);
    float* b1  = (float*)(BI + 5760);
    float* b2  = (float*)(BI + 6560);

    // ---- 0. conversions + biases + state-zero (2 kernels) ----
    if (pre)
        conv_a0<<<16384, 256, 0, stream>>>(ast, A0hi, A0lo);
    prep_all<<<(2128176 + 255) / 256, 256, 0, stream>>>(
        ce_w0, ce_w1, ce_w2, ce_w3, cl_Wih, cl_Whh, nl_Wih, nl_Whh,
        cc_w0, cc_w1, rg_w0, rg_w1,
        cl_bih, cl_bhh, nl_bih, nl_bhh, cc_b0, no_nodes, no_comps,
        w0hi, w0lo, w1hi, w1lo, w2hi, w2lo, w3hi, w3lo,
        wiC_h, wiC_l, whC_h, whC_l, wiN_h, wiN_l, whN_h, whN_l,
        c0L_h, c0L_l, c0I_h, c0I_l, c1_h, c1_l, rg0_h, rg0_l, rg1_h, rg1_l,
        clb, nlb, b1, b2, S);

    dim3 blk(256);
    const int SH = 65536;   // dynamic LDS for gemm_lds

    // ---- 1. comp-embedding MLP (ELU fused, bf16-pair epilogue) ----
    if (pre)
        gemm_lds<true><<<dim3(5, 128), blk, SH, stream>>>(
            A0hi, A0lo, 1024, w0hi, w0lo, 1024, ce_b0,
            nullptr, A1hi, A1lo, 608, 600, 1024, 1);
    else
        gemm_mfma_f32a<<<dim3(5, 128), blk, 0, stream>>>(
            ast, 1024, w0hi, w0lo, 1024, ce_b0,
            A1hi, A1lo, 608, 600, 1024, 1);
    gemm_lds<true><<<dim3(3, 128), blk, SH, stream>>>(
        A1hi, A1lo, 608, w1hi, w1lo, 608, ce_b1,
        nullptr, A2hi, A2lo, 352, 350, 608, 1);
    gemm_lds<true><<<dim3(2, 128), blk, SH, stream>>>(
        A2hi, A2lo, 352, w2hi, w2lo, 352, ce_b2,
        nullptr, A3hi, A3lo, 224, 200, 352, 1);
    gemm_lds<true><<<dim3(2, 128), blk, SH, stream>>>(
        A3hi, A3lo, 224, w3hi, w3lo, 224, ce_b3,
        nullptr, EMhi, EMlo, 192, 180, 224, 1);

    // ---- 2. leaf LSTM: batch 1536 (6 leaves x 256), T=8 ----
    gather_leaf_bf<<<(12288*192 + 255)/256, 256, 0, stream>>>(EMhi, EMlo, XGhi, XGlo);
    gemm_lds<false><<<dim3(6, 96), blk, SH, stream>>>(
        XGhi, XGlo, 192, wiC_h, wiC_l, 192, clb,
        XWl, nullptr, nullptr, 0, 720, 192, 0);
    for (int t = 0; t < 8; ++t) {
        if (t > 0)
            gemm_lds<false><<<dim3(6, 12), blk, SH, stream>>>(
                hl_hi, hl_lo, 192, whC_h, whC_l, 192, nullptr,
                G, nullptr, nullptr, 0, 720, 192, 0);
        lstm_gate<<<(1536*180 + 255)/256, 256, 0, stream>>>(
            hl_hi, hl_lo, c_l, t ? G : nullptr, XWl, 1536, 8, t);
    }
    // leaf concat: comps half of cc_w0, no_nodes folded in b1
    gemm_lds<true><<<dim3(2, 12), blk, SH, stream>>>(
        hl_hi, hl_lo, 192, c0L_h, c0L_l, 192, b1,
        nullptr, y2_hi, y2_lo, 224, 200, 192, 1);
    gemm_lds<true><<<dim3(2, 12), blk, SH, stream>>>(
        y2_hi, y2_lo, 224, c1_h, c1_l, 224, cc_b1,
        nullptr, ls_hi, ls_lo, 192, 180, 224, 1);

    // ---- 3. mid LSTM: batch 768 (3 mids x 256), T=2 ----
    gather_mid_bf<<<(1536*192 + 255)/256, 256, 0, stream>>>(ls_hi, ls_lo, x2_hi, x2_lo);
    gemm_lds<false><<<dim3(6, 12), blk, SH, stream>>>(
        x2_hi, x2_lo, 192, wiN_h, wiN_l, 192, nlb,
        XW2, nullptr, nullptr, 0, 720, 192, 0);
    for (int t = 0; t < 2; ++t) {
        if (t > 0)
            gemm_lds<false><<<dim3(6, 6), blk, SH, stream>>>(
                hm_hi, hm_lo, 192, whN_h, whN_l, 192, nullptr,
                G, nullptr, nullptr, 0, 720, 192, 0);
        lstm_gate<<<(768*180 + 255)/256, 256, 0, stream>>>(
            hm_hi, hm_lo, c_m, t ? G : nullptr, XW2, 768, 2, t);
    }
    // interior concat: nodes half of cc_w0, no_comps folded in b2
    gemm_lds<true><<<dim3(2, 6), blk, SH, stream>>>(
        hm_hi, hm_lo, 192, c0I_h, c0I_l, 192, b2,
        nullptr, y2_hi, y2_lo, 224, 200, 192, 1);
    gemm_lds<true><<<dim3(2, 6), blk, SH, stream>>>(
        y2_hi, y2_lo, 224, c1_h, c1_l, 224, cc_b1,
        nullptr, ms_hi, ms_lo, 192, 180, 224, 1);

    // ---- 4. root LSTM: batch 256, T=3 ----
    gather_root_bf<<<(768*192 + 255)/256, 256, 0, stream>>>(ms_hi, ms_lo, x3_hi, x3_lo);
    gemm_lds<false><<<dim3(6, 6), blk, SH, stream>>>(
        x3_hi, x3_lo, 192, wiN_h, wiN_l, 192, nlb,
        XW3, nullptr, nullptr, 0, 720, 192, 0);
    for (int t = 0; t < 3; ++t) {
        if (t > 0)
            gemm_lds<false><<<dim3(6, 2), blk, SH, stream>>>(
                hr_hi, hr_lo, 192, whN_h, whN_l, 192, nullptr,
                G, nullptr, nullptr, 0, 720, 192, 0);
        lstm_gate<<<(256*180 + 255)/256, 256, 0, stream>>>(
            hr_hi, hr_lo, c_r, t ? G : nullptr, XW3, 256, 3, t);
    }
    gemm_lds<true><<<dim3(2, 2), blk, SH, stream>>>(
        hr_hi, hr_lo, 192, c0I_h, c0I_l, 192, b2,
        nullptr, y2_hi, y2_lo, 224, 200, 192, 1);
    gemm_lds<true><<<dim3(2, 2), blk, SH, stream>>>(
        y2_hi, y2_lo, 224, c1_h, c1_l, 224, cc_b1,
        nullptr, pg_hi, pg_lo, 192, 180, 224, 1);

    // ---- 5. regression + prediction ----
    gemm_lds<true><<<dim3(2, 2), blk, SH, stream>>>(
        pg_hi, pg_lo, 192, rg0_h, rg0_l, 192, rg_b0,
        nullptr, r2_hi, r2_lo, 224, 200, 192, 1);
    gemm_lds<false><<<dim3(2, 2), blk, SH, stream>>>(
        r2_hi, r2_lo, 224, rg1_h, rg1_l, 224, rg_b1,
        r180, nullptr, nullptr, 0, 180, 224, 1);
    pred_kernel<<<1, 256, 0, stream>>>(r180, pred_w, pred_b, out);
}